// Round 6
// baseline (190.731 us; speedup 1.0000x reference)
//
#include <hip/hip_runtime.h>
#include <stdint.h>

// ---------------------------------------------------------------------------
// Fused MHA block: x@Wq^T / x@Wk^T*scale / x@Wv^T -> causal attention with
// torch-style v.reshape(B,S,D,H) head split -> LayerNorm -> @Wo^T.
// B=4 S=1024 E=1024 H=16 D=64. All heavy math in bf16 MFMA, fp32 accum.
// ---------------------------------------------------------------------------

using bf16x8 = __attribute__((ext_vector_type(8))) short;
using f32x4  = __attribute__((ext_vector_type(4))) float;
using u16x8  = __attribute__((ext_vector_type(8))) unsigned short;

#define AS1 __attribute__((address_space(1)))
#define AS3 __attribute__((address_space(3)))

__device__ __forceinline__ void gload16(const void* g, void* l) {
  // async global->LDS, 16B per lane; LDS dest is wave-uniform base + lane*16
  __builtin_amdgcn_global_load_lds((const AS1 uint32_t*)g, (AS3 uint32_t*)l, 16, 0, 0);
}

__device__ __forceinline__ unsigned short f2bf(float f) {  // RNE f32->bf16
  union { float f; uint32_t u; } v; v.f = f;
  uint32_t u = v.u + 0x7fffu + ((v.u >> 16) & 1u);
  return (unsigned short)(u >> 16);
}
__device__ __forceinline__ float bf2f(unsigned short h) {
  union { uint32_t u; float f; } v; v.u = ((uint32_t)h) << 16;
  return v.f;
}

// ---------------- fused fp32 -> bf16 converts (one launch) ------------------
// regions (float4 units): x 1048576 | Wq 262144 | Wk 262144 (x0.125)
//                         | Wv 262144 | Wo 262144
__global__ __launch_bounds__(256) void cvt_all(const float* __restrict__ x,
                                               const float* __restrict__ Wq,
                                               const float* __restrict__ Wk,
                                               const float* __restrict__ Wv,
                                               const float* __restrict__ Wo,
                                               unsigned short* __restrict__ xb,
                                               unsigned short* __restrict__ wcat,
                                               unsigned short* __restrict__ wob) {
  int i = (int)blockIdx.x * 256 + (int)threadIdx.x;   // 2097152 total
  const float* src; unsigned short* dst; int off; float scale = 1.0f;
  if (i < 1048576)      { src = x;  dst = xb;             off = i; }
  else if (i < 1310720) { src = Wq; dst = wcat;           off = i - 1048576; }
  else if (i < 1572864) { src = Wk; dst = wcat + 1048576; off = i - 1310720; scale = 0.125f; }
  else if (i < 1835008) { src = Wv; dst = wcat + 2097152; off = i - 1572864; }
  else                  { src = Wo; dst = wob;            off = i - 1835008; }
  float4 v = reinterpret_cast<const float4*>(src)[off];
  ushort4 o;
  o.x = f2bf(v.x * scale);
  o.y = f2bf(v.y * scale);
  o.z = f2bf(v.z * scale);
  o.w = f2bf(v.w * scale);
  reinterpret_cast<ushort4*>(dst)[off] = o;
}

// ---------------- GEMM (A[M,K] * B[N,K]^T), dbuf BK=64 ----------------------
// 128x128 tile, BK=64, double-buffered LDS (64KB), prefetch next K-tile at
// loop top, compute current, one __syncthreads per iteration (same proven
// staging pattern as attn_fwd). LDS reads 2-way-max conflicts via the
// slot^(row&7) involution (source pre-swizzled, rule #21).
template<int OUTF32>
__global__ __launch_bounds__(256, 2) void gemm_bt(const unsigned short* __restrict__ A,
                                                  const unsigned short* __restrict__ B,
                                                  void* __restrict__ Cv,
                                                  int M, int N, int K) {
  (void)M;
  __shared__ __align__(16) unsigned short lA[2][128 * 64];
  __shared__ __align__(16) unsigned short lB[2][128 * 64];
  const int tn_cnt = N >> 7;
  const int nwg = gridDim.x;
  int bid = (int)blockIdx.x;
  int bid2 = (bid & 7) * (nwg >> 3) + (bid >> 3);   // XCD swizzle (nwg%8==0)
  int tm = bid2 / tn_cnt, tn = bid2 % tn_cnt;
  int t = (int)threadIdx.x;
  int w = t >> 6, lane = t & 63, lr = lane & 15, hi = lane >> 4;
  int wr = w >> 1, wc = w & 1;

  auto stage = [&](int kt, int buf) {
#pragma unroll
    for (int j = 0; j < 4; ++j) {
      int ch = j * 256 + t;
      int row = ch >> 3, slot = ch & 7;
      gload16(A + (size_t)(tm * 128 + row) * K + kt * 64 + ((slot ^ (row & 7)) << 3),
              (char*)lA[buf] + j * 4096 + w * 1024);
    }
#pragma unroll
    for (int j = 0; j < 4; ++j) {
      int ch = j * 256 + t;
      int row = ch >> 3, slot = ch & 7;
      gload16(B + (size_t)(tn * 128 + row) * K + kt * 64 + ((slot ^ (row & 7)) << 3),
              (char*)lB[buf] + j * 4096 + w * 1024);
    }
  };

  f32x4 acc[4][4] = {};
  stage(0, 0);
  __syncthreads();
  const int NT = K >> 6;
  for (int kt = 0; kt < NT; ++kt) {
    int cur = kt & 1;
    if (kt + 1 < NT) stage(kt + 1, cur ^ 1);
    const char* pa = (const char*)lA[cur];
    const char* pb = (const char*)lB[cur];
#pragma unroll
    for (int kc = 0; kc < 2; ++kc) {
      bf16x8 af[4], bfr[4];
#pragma unroll
      for (int mi = 0; mi < 4; ++mi) {
        int row = wr * 64 + mi * 16 + lr;
        int slot = (kc * 4 + hi) ^ (row & 7);
        af[mi] = *reinterpret_cast<const bf16x8*>(pa + row * 128 + slot * 16);
      }
#pragma unroll
      for (int ni = 0; ni < 4; ++ni) {
        int row = wc * 64 + ni * 16 + lr;
        int slot = (kc * 4 + hi) ^ (row & 7);
        bfr[ni] = *reinterpret_cast<const bf16x8*>(pb + row * 128 + slot * 16);
      }
#pragma unroll
      for (int mi = 0; mi < 4; ++mi)
#pragma unroll
        for (int ni = 0; ni < 4; ++ni)
          acc[mi][ni] = __builtin_amdgcn_mfma_f32_16x16x32_bf16(af[mi], bfr[ni], acc[mi][ni], 0, 0, 0);
    }
    __syncthreads();
  }
  // C/D layout: col = lane&15, row = (lane>>4)*4 + reg   [m89-verified]
#pragma unroll
  for (int mi = 0; mi < 4; ++mi) {
#pragma unroll
    for (int r = 0; r < 4; ++r) {
      size_t row = (size_t)(tm * 128 + wr * 64 + mi * 16 + hi * 4 + r);
#pragma unroll
      for (int ni = 0; ni < 4; ++ni) {
        int col = tn * 128 + wc * 64 + ni * 16 + lr;
        float v = acc[mi][ni][r];
        if (OUTF32) reinterpret_cast<float*>(Cv)[row * N + col] = v;
        else        reinterpret_cast<unsigned short*>(Cv)[row * N + col] = f2bf(v);
      }
    }
  }
}

// ---------------- V repack: QKV v-part [s][d*16+h] -> VhT [b,h][d][s] -------
__global__ __launch_bounds__(256) void vrepack(const unsigned short* __restrict__ QKV,
                                               unsigned short* __restrict__ VhT) {
  __shared__ __align__(16) unsigned short lT[64 * 72];   // +8 pad vs 64
  int st = (int)blockIdx.x;   // s-tile (16)
  int ct = (int)blockIdx.y;   // c-tile (16)
  int b  = (int)blockIdx.z;   // batch (4)
  int t = (int)threadIdx.x;
#pragma unroll
  for (int i = 0; i < 2; ++i) {
    int c = i * 256 + t;
    int row = c >> 3, ch = c & 7;
    u16x8 v = *reinterpret_cast<const u16x8*>(
        QKV + (size_t)(b * 1024 + st * 64 + row) * 3072 + 2048 + ct * 64 + ch * 8);
    *reinterpret_cast<u16x8*>(&lT[row * 72 + ch * 8]) = v;
  }
  __syncthreads();
#pragma unroll
  for (int i = 0; i < 2; ++i) {
    int c2 = i * 256 + t;
    int cl = c2 >> 3, ch = c2 & 7;
    int h = cl & 15;
    int d = ct * 4 + (cl >> 4);
    u16x8 v;
#pragma unroll
    for (int j = 0; j < 8; ++j) v[j] = lT[(ch * 8 + j) * 72 + cl];
    *reinterpret_cast<u16x8*>(
        VhT + (size_t)((b * 16 + h) * 64 + d) * 1024 + st * 64 + ch * 8) = v;
  }
}

// ---------------- flash attention (causal), bf16 MFMA -----------------------
// grid 512: bid -> (bh, qt) with qt = (bid>>8)? (bid&3) : 7-(bid&3) so blocks
// bid and bid+256 have complementary work (load balance across CUs).
// K/V double-buffered in LDS; next tile prefetched at loop top, one
// __syncthreads() per iteration.
// All LDS tiles XOR-swizzled: byte ^= (row&7)<<4; global_load_lds sources are
// pre-swizzled with the same involution (rule #21).
__global__ __launch_bounds__(256, 2) void attn_fwd(const unsigned short* __restrict__ QKV,
                                                   const unsigned short* __restrict__ VhT,
                                                   unsigned short* __restrict__ Out) {
  __shared__ __align__(16) unsigned short lQ[128 * 64];
  __shared__ __align__(16) unsigned short lK[2][64 * 64];
  __shared__ __align__(16) unsigned short lV[2][64 * 64];
  __shared__ __align__(16) unsigned short lP[4][32 * 64];
  int bid = (int)blockIdx.x;
  int half = bid >> 8, idx = bid & 255;
  int bh = idx >> 2, jj = idx & 3;
  int qt = half ? jj : 7 - jj;
  int b = bh >> 4, h = bh & 15;
  int t = (int)threadIdx.x;
  int w = t >> 6, lane = t & 63, lr = lane & 15, hi = lane >> 4;
  (void)lane;

  auto stageKV = [&](int kb, int buf) {
#pragma unroll
    for (int i = 0; i < 2; ++i) {
      int c = i * 256 + t;
      int row = c >> 3, slot = c & 7;
      gload16(QKV + (size_t)(b * 1024 + kb * 64 + row) * 3072 + 1024 + h * 64 + ((slot ^ (row & 7)) << 3),
              (char*)lK + buf * 8192 + i * 4096 + w * 1024);
    }
#pragma unroll
    for (int i = 0; i < 2; ++i) {
      int c = i * 256 + t;
      int row = c >> 3, slot = c & 7;
      gload16(VhT + (size_t)(bh * 64 + row) * 1024 + kb * 64 + ((slot ^ (row & 7)) << 3),
              (char*)lV + buf * 8192 + i * 4096 + w * 1024);
    }
  };

  // ---- stage Q tile [128][64] + first K/V tile ----
#pragma unroll
  for (int i = 0; i < 4; ++i) {
    int c = i * 256 + t;
    int row = c >> 3, slot = c & 7;
    gload16(QKV + (size_t)(b * 1024 + qt * 128 + row) * 3072 + h * 64 + ((slot ^ (row & 7)) << 3),
            (char*)lQ + i * 4096 + w * 1024);
  }
  stageKV(0, 0);
  __syncthreads();

  // ---- Q fragments to registers (A-operand: row=lane&15, k=(lane>>4)*8+j) --
  bf16x8 qfr[2][2];
#pragma unroll
  for (int qf = 0; qf < 2; ++qf)
#pragma unroll
    for (int kc = 0; kc < 2; ++kc) {
      int row = w * 32 + qf * 16 + lr;
      int slot = (kc * 4 + hi) ^ (row & 7);
      qfr[qf][kc] = *reinterpret_cast<const bf16x8*>((const char*)lQ + row * 128 + slot * 16);
    }
  int qbase = qt * 128 + w * 32;
  f32x4 o[2][4] = {};
  float mrun[2][4], lpart[2][4];
#pragma unroll
  for (int qf = 0; qf < 2; ++qf)
#pragma unroll
    for (int r = 0; r < 4; ++r) { mrun[qf][r] = -1e30f; lpart[qf][r] = 0.f; }

  int nkb = 2 * qt + 2;
  for (int kb = 0; kb < nkb; ++kb) {
    int cur = kb & 1;
    // ---- prefetch next K/V tile into the other buffer ----
    if (kb + 1 < nkb) stageKV(kb + 1, cur ^ 1);
    if (kb * 64 <= qbase + 31) {   // wave has unmasked work
      const char* kbuf = (const char*)lK + cur * 8192;
      const char* vbuf = (const char*)lV + cur * 8192;
      // ---- S = Q K^T ----
      bf16x8 kfr[4][2];
#pragma unroll
      for (int nf = 0; nf < 4; ++nf)
#pragma unroll
        for (int kc = 0; kc < 2; ++kc) {
          int row = nf * 16 + lr;
          int slot = (kc * 4 + hi) ^ (row & 7);
          kfr[nf][kc] = *reinterpret_cast<const bf16x8*>(kbuf + row * 128 + slot * 16);
        }
      f32x4 s[2][4] = {};
#pragma unroll
      for (int qf = 0; qf < 2; ++qf)
#pragma unroll
        for (int nf = 0; nf < 4; ++nf)
#pragma unroll
          for (int kc = 0; kc < 2; ++kc)
            s[qf][nf] = __builtin_amdgcn_mfma_f32_16x16x32_bf16(qfr[qf][kc], kfr[nf][kc], s[qf][nf], 0, 0, 0);
      // ---- V fragments issued early (overlap with softmax VALU) ----
      bf16x8 vfr[4][2];
#pragma unroll
      for (int df = 0; df < 4; ++df)
#pragma unroll
        for (int kc = 0; kc < 2; ++kc) {
          int row = df * 16 + lr;
          int slot = (kc * 4 + hi) ^ (row & 7);
          vfr[df][kc] = *reinterpret_cast<const bf16x8*>(vbuf + row * 128 + slot * 16);
        }
      // ---- causal mask (diagonal blocks only) ----
      if (kb * 64 + 63 > qbase) {
#pragma unroll
        for (int qf = 0; qf < 2; ++qf)
#pragma unroll
          for (int nf = 0; nf < 4; ++nf)
#pragma unroll
            for (int r = 0; r < 4; ++r) {
              int q = qbase + qf * 16 + hi * 4 + r;
              int kv = kb * 64 + nf * 16 + lr;
              if (kv > q) s[qf][nf][r] = -1e30f;
            }
      }
      // ---- online softmax ----
#pragma unroll
      for (int qf = 0; qf < 2; ++qf) {
        float rm[4];
#pragma unroll
        for (int r = 0; r < 4; ++r)
          rm[r] = fmaxf(fmaxf(s[qf][0][r], s[qf][1][r]), fmaxf(s[qf][2][r], s[qf][3][r]));
#pragma unroll
        for (int r = 0; r < 4; ++r) {
          rm[r] = fmaxf(rm[r], __shfl_xor(rm[r], 1));
          rm[r] = fmaxf(rm[r], __shfl_xor(rm[r], 2));
          rm[r] = fmaxf(rm[r], __shfl_xor(rm[r], 4));
          rm[r] = fmaxf(rm[r], __shfl_xor(rm[r], 8));
        }
#pragma unroll
        for (int r = 0; r < 4; ++r) {
          float mn = fmaxf(mrun[qf][r], rm[r]);
          float al = __expf(mrun[qf][r] - mn);
          mrun[qf][r] = mn;
          float ps = 0.f;
#pragma unroll
          for (int nf = 0; nf < 4; ++nf) {
            float p = __expf(s[qf][nf][r] - mn);
            s[qf][nf][r] = p;
            ps += p;
          }
          lpart[qf][r] = lpart[qf][r] * al + ps;
#pragma unroll
          for (int df = 0; df < 4; ++df) o[qf][df][r] *= al;
        }
      }
      // ---- P (bf16) -> wave-private LDS slab, swizzled ----
      char* pb = (char*)lP[w];
#pragma unroll
      for (int qf = 0; qf < 2; ++qf)
#pragma unroll
        for (int nf = 0; nf < 4; ++nf)
#pragma unroll
          for (int r = 0; r < 4; ++r) {
            int rp = qf * 16 + hi * 4 + r;
            int col = nf * 16 + lr;
            int slot = (col >> 3) ^ (rp & 7);
            *reinterpret_cast<unsigned short*>(pb + rp * 128 + slot * 16 + (col & 7) * 2) =
                f2bf(s[qf][nf][r]);
          }
      asm volatile("s_waitcnt lgkmcnt(0)" ::: "memory");
      __builtin_amdgcn_sched_barrier(0);
      // ---- O += P V ----
      bf16x8 pfr[2][2];
#pragma unroll
      for (int qf = 0; qf < 2; ++qf)
#pragma unroll
        for (int kc = 0; kc < 2; ++kc) {
          int row = qf * 16 + lr;
          int slot = (kc * 4 + hi) ^ (row & 7);
          pfr[qf][kc] = *reinterpret_cast<const bf16x8*>(pb + row * 128 + slot * 16);
        }
#pragma unroll
      for (int qf = 0; qf < 2; ++qf)
#pragma unroll
        for (int df = 0; df < 4; ++df)
#pragma unroll
          for (int kc = 0; kc < 2; ++kc)
            o[qf][df] = __builtin_amdgcn_mfma_f32_16x16x32_bf16(pfr[qf][kc], vfr[df][kc], o[qf][df], 0, 0, 0);
    }
    // ---- end of iteration: full fence + barrier (drains prefetch vmcnt) ----
    __syncthreads();
  }

  // ---- finalize: full row-sum, normalize, store bf16 [b,t][h*64+d] ----
#pragma unroll
  for (int qf = 0; qf < 2; ++qf)
#pragma unroll
    for (int r = 0; r < 4; ++r) {
      float l = lpart[qf][r];
      l += __shfl_xor(l, 1);
      l += __shfl_xor(l, 2);
      l += __shfl_xor(l, 4);
      l += __shfl_xor(l, 8);
      float inv = 1.0f / l;
      int qrow = qbase + qf * 16 + hi * 4 + r;
#pragma unroll
      for (int df = 0; df < 4; ++df)
        Out[(size_t)(b * 1024 + qrow) * 1024 + h * 64 + df * 16 + lr] = f2bf(o[qf][df][r] * inv);
    }
}

// ---------------- LayerNorm over E=1024, wave per row -----------------------
__global__ __launch_bounds__(256) void lnorm(const unsigned short* __restrict__ X,
                                             unsigned short* __restrict__ Y,
                                             const float* __restrict__ gamma,
                                             const float* __restrict__ beta) {
  int rowi = (int)blockIdx.x * 4 + ((int)threadIdx.x >> 6);
  int lane = (int)threadIdx.x & 63;
  const unsigned short* row = X + (size_t)rowi * 1024;
  u16x8 v0 = reinterpret_cast<const u16x8*>(row)[lane];
  u16x8 v1 = reinterpret_cast<const u16x8*>(row)[lane + 64];
  float f0[8], f1[8];
  float s = 0.f, sq = 0.f;
#pragma unroll
  for (int j = 0; j < 8; ++j) {
    f0[j] = bf2f(v0[j]); f1[j] = bf2f(v1[j]);
    s  += f0[j] + f1[j];
    sq += f0[j] * f0[j] + f1[j] * f1[j];
  }
#pragma unroll
  for (int m = 1; m <= 32; m <<= 1) { s += __shfl_xor(s, m); sq += __shfl_xor(sq, m); }
  float mean = s * (1.0f / 1024.0f);
  float var  = sq * (1.0f / 1024.0f) - mean * mean;
  float rstd = rsqrtf(var + 1e-5f);
  int c0 = lane * 8, c1 = 512 + lane * 8;
  u16x8 o0, o1;
#pragma unroll
  for (int j = 0; j < 8; ++j) {
    o0[j] = f2bf((f0[j] - mean) * rstd * gamma[c0 + j] + beta[c0 + j]);
    o1[j] = f2bf((f1[j] - mean) * rstd * gamma[c1 + j] + beta[c1 + j]);
  }
  reinterpret_cast<u16x8*>(Y + (size_t)rowi * 1024)[lane]      = o0;
  reinterpret_cast<u16x8*>(Y + (size_t)rowi * 1024)[lane + 64] = o1;
}

// ---------------------------------------------------------------------------
extern "C" void kernel_launch(void* const* d_in, const int* in_sizes, int n_in,
                              void* d_out, int out_size, void* d_ws, size_t ws_size,
                              hipStream_t stream) {
  (void)in_sizes; (void)n_in; (void)out_size; (void)ws_size;
  const float* x     = (const float*)d_in[0];
  const float* Wq    = (const float*)d_in[1];
  const float* Wk    = (const float*)d_in[2];
  const float* Wv    = (const float*)d_in[3];
  const float* Wo    = (const float*)d_in[4];
  const float* gamma = (const float*)d_in[5];
  const float* beta  = (const float*)d_in[6];
  char* ws = (char*)d_ws;
  unsigned short* xb   = (unsigned short*)(ws);                    //  8MB [0,8)
  unsigned short* wcat = (unsigned short*)(ws + (8u  << 20));      //  6MB [8,14)
  unsigned short* wob  = (unsigned short*)(ws + (14u << 20));      //  2MB [14,16)
  unsigned short* qkv  = (unsigned short*)(ws + (16u << 20));      // 24MB [16,40)
  unsigned short* vht  = (unsigned short*)(ws + (40u << 20));      //  8MB [40,48)
  unsigned short* att  = (unsigned short*)(ws + (48u << 20));      //  8MB [48,56)
  unsigned short* lnb  = (unsigned short*)(ws + (56u << 20));      //  8MB [56,64)

  // fused converts (scale 1/sqrt(64)=0.125 folded into Wk)
  cvt_all<<<8192, 256, 0, stream>>>(x, Wq, Wk, Wv, Wo, xb, wcat, wob);
  // QKV projection: [4096,1024] x [3072,1024]^T -> bf16 [4096,3072]
  gemm_bt<0><<<768, 256, 0, stream>>>(xb, wcat, qkv, 4096, 3072, 1024);
  // V head-transpose repack
  vrepack<<<dim3(16, 16, 4), 256, 0, stream>>>(qkv, vht);
  // causal flash attention
  attn_fwd<<<512, 256, 0, stream>>>(qkv, vht, att);
  // LayerNorm
  lnorm<<<1024, 256, 0, stream>>>(att, lnb, gamma, beta);
  // output projection -> fp32 d_out
  gemm_bt<1><<<256, 256, 0, stream>>>(lnb, wob, (void*)d_out, 4096, 1024, 1024);
}

// Round 7
// 186.005 us; speedup vs baseline: 1.0254x; 1.0254x over previous
//
#include <hip/hip_runtime.h>
#include <stdint.h>

// ---------------------------------------------------------------------------
// Fused MHA block: x@Wq^T / x@Wk^T*scale / x@Wv^T -> causal attention with
// torch-style v.reshape(B,S,D,H) head split -> LayerNorm -> @Wo^T.
// B=4 S=1024 E=1024 H=16 D=64. All heavy math in bf16 MFMA, fp32 accum.
// ---------------------------------------------------------------------------

using bf16x8 = __attribute__((ext_vector_type(8))) short;
using f32x4  = __attribute__((ext_vector_type(4))) float;
using u16x8  = __attribute__((ext_vector_type(8))) unsigned short;

#define AS1 __attribute__((address_space(1)))
#define AS3 __attribute__((address_space(3)))

__device__ __forceinline__ void gload16(const void* g, void* l) {
  // async global->LDS, 16B per lane; LDS dest is wave-uniform base + lane*16
  __builtin_amdgcn_global_load_lds((const AS1 uint32_t*)g, (AS3 uint32_t*)l, 16, 0, 0);
}

__device__ __forceinline__ unsigned short f2bf(float f) {  // RNE f32->bf16
  union { float f; uint32_t u; } v; v.f = f;
  uint32_t u = v.u + 0x7fffu + ((v.u >> 16) & 1u);
  return (unsigned short)(u >> 16);
}
__device__ __forceinline__ float bf2f(unsigned short h) {
  union { uint32_t u; float f; } v; v.u = ((uint32_t)h) << 16;
  return v.f;
}

// ---------------- fused fp32 -> bf16 converts (one launch) ------------------
// regions (float4 units): x 1048576 | Wq 262144 | Wk 262144 (x0.125)
//                         | Wv 262144 | Wo 262144
__global__ __launch_bounds__(256) void cvt_all(const float* __restrict__ x,
                                               const float* __restrict__ Wq,
                                               const float* __restrict__ Wk,
                                               const float* __restrict__ Wv,
                                               const float* __restrict__ Wo,
                                               unsigned short* __restrict__ xb,
                                               unsigned short* __restrict__ wcat,
                                               unsigned short* __restrict__ wob) {
  int i = (int)blockIdx.x * 256 + (int)threadIdx.x;   // 2097152 total
  const float* src; unsigned short* dst; int off; float scale = 1.0f;
  if (i < 1048576)      { src = x;  dst = xb;             off = i; }
  else if (i < 1310720) { src = Wq; dst = wcat;           off = i - 1048576; }
  else if (i < 1572864) { src = Wk; dst = wcat + 1048576; off = i - 1310720; scale = 0.125f; }
  else if (i < 1835008) { src = Wv; dst = wcat + 2097152; off = i - 1572864; }
  else                  { src = Wo; dst = wob;            off = i - 1835008; }
  float4 v = reinterpret_cast<const float4*>(src)[off];
  ushort4 o;
  o.x = f2bf(v.x * scale);
  o.y = f2bf(v.y * scale);
  o.z = f2bf(v.z * scale);
  o.w = f2bf(v.w * scale);
  reinterpret_cast<ushort4*>(dst)[off] = o;
}

// ---------------- GEMM (A[M,K] * B[N,K]^T), dbuf BK=32 ----------------------
// TM x 128 tile, BK=32, double-buffered LDS (TM=128 -> 32KB -> 3 blocks/CU
// resident; barrier stalls of one block hide under compute of the others).
// Prefetch next K-tile at loop top, one __syncthreads per iteration.
// LDS swizzle: slot ^ (row&3) involution, source pre-swizzled (rule #21);
// wave b128 reads run at the 8-clk LDS BW floor.
template<int OUTF32, int TM>
__global__ __launch_bounds__(256, 3) void gemm_bt(const unsigned short* __restrict__ A,
                                                  const unsigned short* __restrict__ B,
                                                  void* __restrict__ Cv,
                                                  int N, int K) {
  constexpr int MI = TM / 32;   // 16-row fragments per wave in M
  __shared__ __align__(16) unsigned short lA[2][TM * 32];
  __shared__ __align__(16) unsigned short lB[2][128 * 32];
  const int tn_cnt = N >> 7;
  const int nwg = gridDim.x;
  int bid = (int)blockIdx.x;
  int bid2 = (bid & 7) * (nwg >> 3) + (bid >> 3);   // XCD swizzle (nwg%8==0)
  int tm = bid2 / tn_cnt, tn = bid2 % tn_cnt;
  int t = (int)threadIdx.x;
  int w = t >> 6, lane = t & 63, lr = lane & 15, hi = lane >> 4;
  int wr = w >> 1, wc = w & 1;

  auto stage = [&](int kt, int buf) {
#pragma unroll
    for (int j = 0; j < TM / 64; ++j) {
      int ch = j * 256 + t;
      int row = ch >> 2, slot = ch & 3;
      gload16(A + (size_t)(tm * TM + row) * K + kt * 32 + ((slot ^ (row & 3)) << 3),
              (char*)lA[buf] + j * 4096 + w * 1024);
    }
#pragma unroll
    for (int j = 0; j < 2; ++j) {
      int ch = j * 256 + t;
      int row = ch >> 2, slot = ch & 3;
      gload16(B + (size_t)(tn * 128 + row) * K + kt * 32 + ((slot ^ (row & 3)) << 3),
              (char*)lB[buf] + j * 4096 + w * 1024);
    }
  };

  f32x4 acc[MI][4] = {};
  stage(0, 0);
  __syncthreads();
  const int NT = K >> 5;
  for (int kt = 0; kt < NT; ++kt) {
    int cur = kt & 1;
    if (kt + 1 < NT) stage(kt + 1, cur ^ 1);
    const char* pa = (const char*)lA[cur];
    const char* pb = (const char*)lB[cur];
    bf16x8 af[MI], bfr[4];
#pragma unroll
    for (int mi = 0; mi < MI; ++mi) {
      int row = wr * (TM / 2) + mi * 16 + lr;
      int slot = hi ^ (row & 3);
      af[mi] = *reinterpret_cast<const bf16x8*>(pa + row * 64 + slot * 16);
    }
#pragma unroll
    for (int ni = 0; ni < 4; ++ni) {
      int row = wc * 64 + ni * 16 + lr;
      int slot = hi ^ (row & 3);
      bfr[ni] = *reinterpret_cast<const bf16x8*>(pb + row * 64 + slot * 16);
    }
#pragma unroll
    for (int mi = 0; mi < MI; ++mi)
#pragma unroll
      for (int ni = 0; ni < 4; ++ni)
        acc[mi][ni] = __builtin_amdgcn_mfma_f32_16x16x32_bf16(af[mi], bfr[ni], acc[mi][ni], 0, 0, 0);
    __syncthreads();
  }
  // C/D layout: col = lane&15, row = (lane>>4)*4 + reg   [m89-verified]
#pragma unroll
  for (int mi = 0; mi < MI; ++mi) {
#pragma unroll
    for (int r = 0; r < 4; ++r) {
      size_t row = (size_t)(tm * TM + wr * (TM / 2) + mi * 16 + hi * 4 + r);
#pragma unroll
      for (int ni = 0; ni < 4; ++ni) {
        int col = tn * 128 + wc * 64 + ni * 16 + lr;
        float v = acc[mi][ni][r];
        if (OUTF32) reinterpret_cast<float*>(Cv)[row * N + col] = v;
        else        reinterpret_cast<unsigned short*>(Cv)[row * N + col] = f2bf(v);
      }
    }
  }
}

// ---------------- V repack: QKV v-part [s][d*16+h] -> VhT [b,h][d][s] -------
__global__ __launch_bounds__(256) void vrepack(const unsigned short* __restrict__ QKV,
                                               unsigned short* __restrict__ VhT) {
  __shared__ __align__(16) unsigned short lT[64 * 72];   // +8 pad vs 64
  int st = (int)blockIdx.x;   // s-tile (16)
  int ct = (int)blockIdx.y;   // c-tile (16)
  int b  = (int)blockIdx.z;   // batch (4)
  int t = (int)threadIdx.x;
#pragma unroll
  for (int i = 0; i < 2; ++i) {
    int c = i * 256 + t;
    int row = c >> 3, ch = c & 7;
    u16x8 v = *reinterpret_cast<const u16x8*>(
        QKV + (size_t)(b * 1024 + st * 64 + row) * 3072 + 2048 + ct * 64 + ch * 8);
    *reinterpret_cast<u16x8*>(&lT[row * 72 + ch * 8]) = v;
  }
  __syncthreads();
#pragma unroll
  for (int i = 0; i < 2; ++i) {
    int c2 = i * 256 + t;
    int cl = c2 >> 3, ch = c2 & 7;
    int h = cl & 15;
    int d = ct * 4 + (cl >> 4);
    u16x8 v;
#pragma unroll
    for (int j = 0; j < 8; ++j) v[j] = lT[(ch * 8 + j) * 72 + cl];
    *reinterpret_cast<u16x8*>(
        VhT + (size_t)((b * 16 + h) * 64 + d) * 1024 + st * 64 + ch * 8) = v;
  }
}

// ---------------- flash attention (causal), bf16 MFMA -----------------------
// grid 512: bid -> (bh, qt) with qt = (bid>>8)? (bid&3) : 7-(bid&3) so blocks
// bid and bid+256 have complementary work (load balance across CUs).
// K/V double-buffered in LDS; next tile prefetched at loop top, one
// __syncthreads() per iteration.
// All LDS tiles XOR-swizzled: byte ^= (row&7)<<4; global_load_lds sources are
// pre-swizzled with the same involution (rule #21).
__global__ __launch_bounds__(256, 2) void attn_fwd(const unsigned short* __restrict__ QKV,
                                                   const unsigned short* __restrict__ VhT,
                                                   unsigned short* __restrict__ Out) {
  __shared__ __align__(16) unsigned short lQ[128 * 64];
  __shared__ __align__(16) unsigned short lK[2][64 * 64];
  __shared__ __align__(16) unsigned short lV[2][64 * 64];
  __shared__ __align__(16) unsigned short lP[4][32 * 64];
  int bid = (int)blockIdx.x;
  int half = bid >> 8, idx = bid & 255;
  int bh = idx >> 2, jj = idx & 3;
  int qt = half ? jj : 7 - jj;
  int b = bh >> 4, h = bh & 15;
  int t = (int)threadIdx.x;
  int w = t >> 6, lane = t & 63, lr = lane & 15, hi = lane >> 4;
  (void)lane;

  auto stageKV = [&](int kb, int buf) {
#pragma unroll
    for (int i = 0; i < 2; ++i) {
      int c = i * 256 + t;
      int row = c >> 3, slot = c & 7;
      gload16(QKV + (size_t)(b * 1024 + kb * 64 + row) * 3072 + 1024 + h * 64 + ((slot ^ (row & 7)) << 3),
              (char*)lK + buf * 8192 + i * 4096 + w * 1024);
    }
#pragma unroll
    for (int i = 0; i < 2; ++i) {
      int c = i * 256 + t;
      int row = c >> 3, slot = c & 7;
      gload16(VhT + (size_t)(bh * 64 + row) * 1024 + kb * 64 + ((slot ^ (row & 7)) << 3),
              (char*)lV + buf * 8192 + i * 4096 + w * 1024);
    }
  };

  // ---- stage Q tile [128][64] + first K/V tile ----
#pragma unroll
  for (int i = 0; i < 4; ++i) {
    int c = i * 256 + t;
    int row = c >> 3, slot = c & 7;
    gload16(QKV + (size_t)(b * 1024 + qt * 128 + row) * 3072 + h * 64 + ((slot ^ (row & 7)) << 3),
            (char*)lQ + i * 4096 + w * 1024);
  }
  stageKV(0, 0);
  __syncthreads();

  // ---- Q fragments to registers (A-operand: row=lane&15, k=(lane>>4)*8+j) --
  bf16x8 qfr[2][2];
#pragma unroll
  for (int qf = 0; qf < 2; ++qf)
#pragma unroll
    for (int kc = 0; kc < 2; ++kc) {
      int row = w * 32 + qf * 16 + lr;
      int slot = (kc * 4 + hi) ^ (row & 7);
      qfr[qf][kc] = *reinterpret_cast<const bf16x8*>((const char*)lQ + row * 128 + slot * 16);
    }
  int qbase = qt * 128 + w * 32;
  f32x4 o[2][4] = {};
  float mrun[2][4], lpart[2][4];
#pragma unroll
  for (int qf = 0; qf < 2; ++qf)
#pragma unroll
    for (int r = 0; r < 4; ++r) { mrun[qf][r] = -1e30f; lpart[qf][r] = 0.f; }

  int nkb = 2 * qt + 2;
  for (int kb = 0; kb < nkb; ++kb) {
    int cur = kb & 1;
    // ---- prefetch next K/V tile into the other buffer ----
    if (kb + 1 < nkb) stageKV(kb + 1, cur ^ 1);
    if (kb * 64 <= qbase + 31) {   // wave has unmasked work
      const char* kbuf = (const char*)lK + cur * 8192;
      const char* vbuf = (const char*)lV + cur * 8192;
      // ---- S = Q K^T ----
      bf16x8 kfr[4][2];
#pragma unroll
      for (int nf = 0; nf < 4; ++nf)
#pragma unroll
        for (int kc = 0; kc < 2; ++kc) {
          int row = nf * 16 + lr;
          int slot = (kc * 4 + hi) ^ (row & 7);
          kfr[nf][kc] = *reinterpret_cast<const bf16x8*>(kbuf + row * 128 + slot * 16);
        }
      f32x4 s[2][4] = {};
#pragma unroll
      for (int qf = 0; qf < 2; ++qf)
#pragma unroll
        for (int nf = 0; nf < 4; ++nf)
#pragma unroll
          for (int kc = 0; kc < 2; ++kc)
            s[qf][nf] = __builtin_amdgcn_mfma_f32_16x16x32_bf16(qfr[qf][kc], kfr[nf][kc], s[qf][nf], 0, 0, 0);
      // ---- V fragments issued early (overlap with softmax VALU) ----
      bf16x8 vfr[4][2];
#pragma unroll
      for (int df = 0; df < 4; ++df)
#pragma unroll
        for (int kc = 0; kc < 2; ++kc) {
          int row = df * 16 + lr;
          int slot = (kc * 4 + hi) ^ (row & 7);
          vfr[df][kc] = *reinterpret_cast<const bf16x8*>(vbuf + row * 128 + slot * 16);
        }
      // ---- causal mask (diagonal blocks only) ----
      if (kb * 64 + 63 > qbase) {
#pragma unroll
        for (int qf = 0; qf < 2; ++qf)
#pragma unroll
          for (int nf = 0; nf < 4; ++nf)
#pragma unroll
            for (int r = 0; r < 4; ++r) {
              int q = qbase + qf * 16 + hi * 4 + r;
              int kv = kb * 64 + nf * 16 + lr;
              if (kv > q) s[qf][nf][r] = -1e30f;
            }
      }
      // ---- online softmax ----
#pragma unroll
      for (int qf = 0; qf < 2; ++qf) {
        float rm[4];
#pragma unroll
        for (int r = 0; r < 4; ++r)
          rm[r] = fmaxf(fmaxf(s[qf][0][r], s[qf][1][r]), fmaxf(s[qf][2][r], s[qf][3][r]));
#pragma unroll
        for (int r = 0; r < 4; ++r) {
          rm[r] = fmaxf(rm[r], __shfl_xor(rm[r], 1));
          rm[r] = fmaxf(rm[r], __shfl_xor(rm[r], 2));
          rm[r] = fmaxf(rm[r], __shfl_xor(rm[r], 4));
          rm[r] = fmaxf(rm[r], __shfl_xor(rm[r], 8));
        }
#pragma unroll
        for (int r = 0; r < 4; ++r) {
          float mn = fmaxf(mrun[qf][r], rm[r]);
          float al = __expf(mrun[qf][r] - mn);
          mrun[qf][r] = mn;
          float ps = 0.f;
#pragma unroll
          for (int nf = 0; nf < 4; ++nf) {
            float p = __expf(s[qf][nf][r] - mn);
            s[qf][nf][r] = p;
            ps += p;
          }
          lpart[qf][r] = lpart[qf][r] * al + ps;
#pragma unroll
          for (int df = 0; df < 4; ++df) o[qf][df][r] *= al;
        }
      }
      // ---- P (bf16) -> wave-private LDS slab, swizzled ----
      char* pb = (char*)lP[w];
#pragma unroll
      for (int qf = 0; qf < 2; ++qf)
#pragma unroll
        for (int nf = 0; nf < 4; ++nf)
#pragma unroll
          for (int r = 0; r < 4; ++r) {
            int rp = qf * 16 + hi * 4 + r;
            int col = nf * 16 + lr;
            int slot = (col >> 3) ^ (rp & 7);
            *reinterpret_cast<unsigned short*>(pb + rp * 128 + slot * 16 + (col & 7) * 2) =
                f2bf(s[qf][nf][r]);
          }
      asm volatile("s_waitcnt lgkmcnt(0)" ::: "memory");
      __builtin_amdgcn_sched_barrier(0);
      // ---- O += P V ----
      bf16x8 pfr[2][2];
#pragma unroll
      for (int qf = 0; qf < 2; ++qf)
#pragma unroll
        for (int kc = 0; kc < 2; ++kc) {
          int row = qf * 16 + lr;
          int slot = (kc * 4 + hi) ^ (row & 7);
          pfr[qf][kc] = *reinterpret_cast<const bf16x8*>(pb + row * 128 + slot * 16);
        }
#pragma unroll
      for (int qf = 0; qf < 2; ++qf)
#pragma unroll
        for (int df = 0; df < 4; ++df)
#pragma unroll
          for (int kc = 0; kc < 2; ++kc)
            o[qf][df] = __builtin_amdgcn_mfma_f32_16x16x32_bf16(pfr[qf][kc], vfr[df][kc], o[qf][df], 0, 0, 0);
    }
    // ---- end of iteration: full fence + barrier (drains prefetch vmcnt) ----
    __syncthreads();
  }

  // ---- finalize: full row-sum, normalize, store bf16 [b,t][h*64+d] ----
#pragma unroll
  for (int qf = 0; qf < 2; ++qf)
#pragma unroll
    for (int r = 0; r < 4; ++r) {
      float l = lpart[qf][r];
      l += __shfl_xor(l, 1);
      l += __shfl_xor(l, 2);
      l += __shfl_xor(l, 4);
      l += __shfl_xor(l, 8);
      float inv = 1.0f / l;
      int qrow = qbase + qf * 16 + hi * 4 + r;
#pragma unroll
      for (int df = 0; df < 4; ++df)
        Out[(size_t)(b * 1024 + qrow) * 1024 + h * 64 + df * 16 + lr] = f2bf(o[qf][df][r] * inv);
    }
}

// ---------------- LayerNorm over E=1024, wave per row -----------------------
__global__ __launch_bounds__(256) void lnorm(const unsigned short* __restrict__ X,
                                             unsigned short* __restrict__ Y,
                                             const float* __restrict__ gamma,
                                             const float* __restrict__ beta) {
  int rowi = (int)blockIdx.x * 4 + ((int)threadIdx.x >> 6);
  int lane = (int)threadIdx.x & 63;
  const unsigned short* row = X + (size_t)rowi * 1024;
  u16x8 v0 = reinterpret_cast<const u16x8*>(row)[lane];
  u16x8 v1 = reinterpret_cast<const u16x8*>(row)[lane + 64];
  float f0[8], f1[8];
  float s = 0.f, sq = 0.f;
#pragma unroll
  for (int j = 0; j < 8; ++j) {
    f0[j] = bf2f(v0[j]); f1[j] = bf2f(v1[j]);
    s  += f0[j] + f1[j];
    sq += f0[j] * f0[j] + f1[j] * f1[j];
  }
#pragma unroll
  for (int m = 1; m <= 32; m <<= 1) { s += __shfl_xor(s, m); sq += __shfl_xor(sq, m); }
  float mean = s * (1.0f / 1024.0f);
  float var  = sq * (1.0f / 1024.0f) - mean * mean;
  float rstd = rsqrtf(var + 1e-5f);
  int c0 = lane * 8, c1 = 512 + lane * 8;
  u16x8 o0, o1;
#pragma unroll
  for (int j = 0; j < 8; ++j) {
    o0[j] = f2bf((f0[j] - mean) * rstd * gamma[c0 + j] + beta[c0 + j]);
    o1[j] = f2bf((f1[j] - mean) * rstd * gamma[c1 + j] + beta[c1 + j]);
  }
  reinterpret_cast<u16x8*>(Y + (size_t)rowi * 1024)[lane]      = o0;
  reinterpret_cast<u16x8*>(Y + (size_t)rowi * 1024)[lane + 64] = o1;
}

// ---------------------------------------------------------------------------
extern "C" void kernel_launch(void* const* d_in, const int* in_sizes, int n_in,
                              void* d_out, int out_size, void* d_ws, size_t ws_size,
                              hipStream_t stream) {
  (void)in_sizes; (void)n_in; (void)out_size; (void)ws_size;
  const float* x     = (const float*)d_in[0];
  const float* Wq    = (const float*)d_in[1];
  const float* Wk    = (const float*)d_in[2];
  const float* Wv    = (const float*)d_in[3];
  const float* Wo    = (const float*)d_in[4];
  const float* gamma = (const float*)d_in[5];
  const float* beta  = (const float*)d_in[6];
  char* ws = (char*)d_ws;
  unsigned short* xb   = (unsigned short*)(ws);                    //  8MB [0,8)
  unsigned short* wcat = (unsigned short*)(ws + (8u  << 20));      //  6MB [8,14)
  unsigned short* wob  = (unsigned short*)(ws + (14u << 20));      //  2MB [14,16)
  unsigned short* qkv  = (unsigned short*)(ws + (16u << 20));      // 24MB [16,40)
  unsigned short* vht  = (unsigned short*)(ws + (40u << 20));      //  8MB [40,48)
  unsigned short* att  = (unsigned short*)(ws + (48u << 20));      //  8MB [48,56)
  unsigned short* lnb  = (unsigned short*)(ws + (56u << 20));      //  8MB [56,64)

  // fused converts (scale 1/sqrt(64)=0.125 folded into Wk)
  cvt_all<<<8192, 256, 0, stream>>>(x, Wq, Wk, Wv, Wo, xb, wcat, wob);
  // QKV projection: [4096,1024] x [3072,1024]^T -> bf16 [4096,3072]
  gemm_bt<0, 128><<<768, 256, 0, stream>>>(xb, wcat, qkv, 3072, 1024);
  // V head-transpose repack
  vrepack<<<dim3(16, 16, 4), 256, 0, stream>>>(qkv, vht);
  // causal flash attention
  attn_fwd<<<512, 256, 0, stream>>>(qkv, vht, att);
  // LayerNorm
  lnorm<<<1024, 256, 0, stream>>>(att, lnb, gamma, beta);
  // output projection -> fp32 d_out (64x128 tile -> grid 512 = 2 blocks/CU)
  gemm_bt<1, 64><<<512, 256, 0, stream>>>(lnb, wob, (void*)d_out, 1024, 1024);
}

// Round 8
// 183.139 us; speedup vs baseline: 1.0415x; 1.0156x over previous
//
#include <hip/hip_runtime.h>
#include <stdint.h>

// ---------------------------------------------------------------------------
// Fused MHA block: x@Wq^T / x@Wk^T*scale / x@Wv^T -> causal attention with
// torch-style v.reshape(B,S,D,H) head split -> LayerNorm -> @Wo^T.
// B=4 S=1024 E=1024 H=16 D=64. All heavy math in bf16 MFMA, fp32 accum.
// ---------------------------------------------------------------------------

using bf16x8 = __attribute__((ext_vector_type(8))) short;
using f32x4  = __attribute__((ext_vector_type(4))) float;
using u16x8  = __attribute__((ext_vector_type(8))) unsigned short;

#define AS1 __attribute__((address_space(1)))
#define AS3 __attribute__((address_space(3)))

__device__ __forceinline__ void gload16(const void* g, void* l) {
  // async global->LDS, 16B per lane; LDS dest is wave-uniform base + lane*16
  __builtin_amdgcn_global_load_lds((const AS1 uint32_t*)g, (AS3 uint32_t*)l, 16, 0, 0);
}

__device__ __forceinline__ unsigned short f2bf(float f) {  // RNE f32->bf16
  union { float f; uint32_t u; } v; v.f = f;
  uint32_t u = v.u + 0x7fffu + ((v.u >> 16) & 1u);
  return (unsigned short)(u >> 16);
}
__device__ __forceinline__ float bf2f(unsigned short h) {
  union { uint32_t u; float f; } v; v.u = ((uint32_t)h) << 16;
  return v.f;
}

// ---------------- fused fp32 -> bf16 converts (one launch) ------------------
// regions (float4 units): x 1048576 | Wq 262144 | Wk 262144 (x0.125)
//                         | Wv 262144 | Wo 262144
__global__ __launch_bounds__(256) void cvt_all(const float* __restrict__ x,
                                               const float* __restrict__ Wq,
                                               const float* __restrict__ Wk,
                                               const float* __restrict__ Wv,
                                               const float* __restrict__ Wo,
                                               unsigned short* __restrict__ xb,
                                               unsigned short* __restrict__ wcat,
                                               unsigned short* __restrict__ wob) {
  int i = (int)blockIdx.x * 256 + (int)threadIdx.x;   // 2097152 total
  const float* src; unsigned short* dst; int off; float scale = 1.0f;
  if (i < 1048576)      { src = x;  dst = xb;             off = i; }
  else if (i < 1310720) { src = Wq; dst = wcat;           off = i - 1048576; }
  else if (i < 1572864) { src = Wk; dst = wcat + 1048576; off = i - 1310720; scale = 0.125f; }
  else if (i < 1835008) { src = Wv; dst = wcat + 2097152; off = i - 1572864; }
  else                  { src = Wo; dst = wob;            off = i - 1835008; }
  float4 v = reinterpret_cast<const float4*>(src)[off];
  ushort4 o;
  o.x = f2bf(v.x * scale);
  o.y = f2bf(v.y * scale);
  o.z = f2bf(v.z * scale);
  o.w = f2bf(v.w * scale);
  reinterpret_cast<ushort4*>(dst)[off] = o;
}

// ---------------- GEMM (A[M,K] * B[N,K]^T), dbuf BK=32 ----------------------
// TM x 128 tile, BK=32, double-buffered LDS, prefetch next K-tile at loop
// top, one __syncthreads per iteration. LDS swizzle: slot ^ (row&3)
// involution, source pre-swizzled (rule #21).
template<int OUTF32, int TM>
__global__ __launch_bounds__(256, 3) void gemm_bt(const unsigned short* __restrict__ A,
                                                  const unsigned short* __restrict__ B,
                                                  void* __restrict__ Cv,
                                                  int N, int K) {
  constexpr int MI = TM / 32;   // 16-row fragments per wave in M
  __shared__ __align__(16) unsigned short lA[2][TM * 32];
  __shared__ __align__(16) unsigned short lB[2][128 * 32];
  const int tn_cnt = N >> 7;
  const int nwg = gridDim.x;
  int bid = (int)blockIdx.x;
  int bid2 = (bid & 7) * (nwg >> 3) + (bid >> 3);   // XCD swizzle (nwg%8==0)
  int tm = bid2 / tn_cnt, tn = bid2 % tn_cnt;
  int t = (int)threadIdx.x;
  int w = t >> 6, lane = t & 63, lr = lane & 15, hi = lane >> 4;
  int wr = w >> 1, wc = w & 1;

  auto stage = [&](int kt, int buf) {
#pragma unroll
    for (int j = 0; j < TM / 64; ++j) {
      int ch = j * 256 + t;
      int row = ch >> 2, slot = ch & 3;
      gload16(A + (size_t)(tm * TM + row) * K + kt * 32 + ((slot ^ (row & 3)) << 3),
              (char*)lA[buf] + j * 4096 + w * 1024);
    }
#pragma unroll
    for (int j = 0; j < 2; ++j) {
      int ch = j * 256 + t;
      int row = ch >> 2, slot = ch & 3;
      gload16(B + (size_t)(tn * 128 + row) * K + kt * 32 + ((slot ^ (row & 3)) << 3),
              (char*)lB[buf] + j * 4096 + w * 1024);
    }
  };

  f32x4 acc[MI][4] = {};
  stage(0, 0);
  __syncthreads();
  const int NT = K >> 5;
  for (int kt = 0; kt < NT; ++kt) {
    int cur = kt & 1;
    if (kt + 1 < NT) stage(kt + 1, cur ^ 1);
    const char* pa = (const char*)lA[cur];
    const char* pb = (const char*)lB[cur];
    bf16x8 af[MI], bfr[4];
#pragma unroll
    for (int mi = 0; mi < MI; ++mi) {
      int row = wr * (TM / 2) + mi * 16 + lr;
      int slot = hi ^ (row & 3);
      af[mi] = *reinterpret_cast<const bf16x8*>(pa + row * 64 + slot * 16);
    }
#pragma unroll
    for (int ni = 0; ni < 4; ++ni) {
      int row = wc * 64 + ni * 16 + lr;
      int slot = hi ^ (row & 3);
      bfr[ni] = *reinterpret_cast<const bf16x8*>(pb + row * 64 + slot * 16);
    }
#pragma unroll
    for (int mi = 0; mi < MI; ++mi)
#pragma unroll
      for (int ni = 0; ni < 4; ++ni)
        acc[mi][ni] = __builtin_amdgcn_mfma_f32_16x16x32_bf16(af[mi], bfr[ni], acc[mi][ni], 0, 0, 0);
    __syncthreads();
  }
  // C/D layout: col = lane&15, row = (lane>>4)*4 + reg   [m89-verified]
#pragma unroll
  for (int mi = 0; mi < MI; ++mi) {
#pragma unroll
    for (int r = 0; r < 4; ++r) {
      size_t row = (size_t)(tm * TM + wr * (TM / 2) + mi * 16 + hi * 4 + r);
#pragma unroll
      for (int ni = 0; ni < 4; ++ni) {
        int col = tn * 128 + wc * 64 + ni * 16 + lr;
        float v = acc[mi][ni][r];
        if (OUTF32) reinterpret_cast<float*>(Cv)[row * N + col] = v;
        else        reinterpret_cast<unsigned short*>(Cv)[row * N + col] = f2bf(v);
      }
    }
  }
}

// ---------------- V repack: QKV v-part [s][d*16+h] -> VhT [b,h][d][s] -------
__global__ __launch_bounds__(256) void vrepack(const unsigned short* __restrict__ QKV,
                                               unsigned short* __restrict__ VhT) {
  __shared__ __align__(16) unsigned short lT[64 * 72];   // +8 pad vs 64
  int st = (int)blockIdx.x;   // s-tile (16)
  int ct = (int)blockIdx.y;   // c-tile (16)
  int b  = (int)blockIdx.z;   // batch (4)
  int t = (int)threadIdx.x;
#pragma unroll
  for (int i = 0; i < 2; ++i) {
    int c = i * 256 + t;
    int row = c >> 3, ch = c & 7;
    u16x8 v = *reinterpret_cast<const u16x8*>(
        QKV + (size_t)(b * 1024 + st * 64 + row) * 3072 + 2048 + ct * 64 + ch * 8);
    *reinterpret_cast<u16x8*>(&lT[row * 72 + ch * 8]) = v;
  }
  __syncthreads();
#pragma unroll
  for (int i = 0; i < 2; ++i) {
    int c2 = i * 256 + t;
    int cl = c2 >> 3, ch = c2 & 7;
    int h = cl & 15;
    int d = ct * 4 + (cl >> 4);
    u16x8 v;
#pragma unroll
    for (int j = 0; j < 8; ++j) v[j] = lT[(ch * 8 + j) * 72 + cl];
    *reinterpret_cast<u16x8*>(
        VhT + (size_t)((b * 16 + h) * 64 + d) * 1024 + st * 64 + ch * 8) = v;
  }
}

// ---------------- flash attention (causal), bf16 MFMA -----------------------
// DISPATCH-ORDER-PROOF BALANCE: grid 512 = 64 (b,h) x 8 pair-ids; every block
// processes TWO complementary 64-row q-tiles (qtA=j, qtB=15-j) so per-block
// work is uniform (17 KV iterations) regardless of block->CU/XCD mapping.
// Per wave: 16 q-rows. K/V double-buffered (prefetch at loop top, one
// __syncthreads per iter). Q and P share one 8KB LDS slab (Q lives in regs
// once the loop starts). LDS total 40KB.
// Swizzle everywhere: byte slot ^ (row&7), sources pre-swizzled (rule #21).
__global__ __launch_bounds__(256, 2) void attn_fwd(const unsigned short* __restrict__ QKV,
                                                   const unsigned short* __restrict__ VhT,
                                                   unsigned short* __restrict__ Out) {
  __shared__ __align__(16) unsigned short lK[2][64 * 64];
  __shared__ __align__(16) unsigned short lV[2][64 * 64];
  __shared__ __align__(16) unsigned short lQP[64 * 64];  // Q (prologue) / P (loop)
  int bid = (int)blockIdx.x;
  int bh = bid >> 3, j = bid & 7;
  int b = bh >> 4, h = bh & 15;
  int t = (int)threadIdx.x;
  int w = t >> 6, lane = t & 63, lr = lane & 15, hi = lane >> 4;
  (void)lane;

  auto stageKV = [&](int kb, int buf) {
#pragma unroll
    for (int i = 0; i < 2; ++i) {
      int c = i * 256 + t;
      int row = c >> 3, slot = c & 7;
      gload16(QKV + (size_t)(b * 1024 + kb * 64 + row) * 3072 + 1024 + h * 64 + ((slot ^ (row & 7)) << 3),
              (char*)lK + buf * 8192 + i * 4096 + w * 1024);
    }
#pragma unroll
    for (int i = 0; i < 2; ++i) {
      int c = i * 256 + t;
      int row = c >> 3, slot = c & 7;
      gload16(VhT + (size_t)(bh * 64 + row) * 1024 + kb * 64 + ((slot ^ (row & 7)) << 3),
              (char*)lV + buf * 8192 + i * 4096 + w * 1024);
    }
  };

#pragma unroll 1
  for (int pass = 0; pass < 2; ++pass) {
    int qt = pass ? (15 - j) : j;       // complementary pair: uniform work
    // ---- stage Q tile [64][64] into lQP + first K/V tile ----
#pragma unroll
    for (int i = 0; i < 2; ++i) {
      int c = i * 256 + t;
      int row = c >> 3, slot = c & 7;
      gload16(QKV + (size_t)(b * 1024 + qt * 64 + row) * 3072 + h * 64 + ((slot ^ (row & 7)) << 3),
              (char*)lQP + i * 4096 + w * 1024);
    }
    stageKV(0, 0);
    __syncthreads();

    // ---- Q fragments (A-operand: row=lane&15, k=(lane>>4)*8+j) ----
    bf16x8 qfr[2];
#pragma unroll
    for (int kc = 0; kc < 2; ++kc) {
      int row = w * 16 + lr;
      int slot = (kc * 4 + hi) ^ (row & 7);
      qfr[kc] = *reinterpret_cast<const bf16x8*>((const char*)lQP + row * 128 + slot * 16);
    }
    int qbase = qt * 64 + w * 16;
    f32x4 o[4] = {};
    float mrun[4], lpart[4];
#pragma unroll
    for (int r = 0; r < 4; ++r) { mrun[r] = -1e30f; lpart[r] = 0.f; }

    int nkb = qt + 1;
    for (int kb = 0; kb < nkb; ++kb) {
      int cur = kb & 1;
      if (kb + 1 < nkb) stageKV(kb + 1, cur ^ 1);
      const char* kbuf = (const char*)lK + cur * 8192;
      const char* vbuf = (const char*)lV + cur * 8192;
      // ---- S = Q K^T ----
      bf16x8 kfr[4][2];
#pragma unroll
      for (int nf = 0; nf < 4; ++nf)
#pragma unroll
        for (int kc = 0; kc < 2; ++kc) {
          int row = nf * 16 + lr;
          int slot = (kc * 4 + hi) ^ (row & 7);
          kfr[nf][kc] = *reinterpret_cast<const bf16x8*>(kbuf + row * 128 + slot * 16);
        }
      f32x4 s[4] = {};
#pragma unroll
      for (int nf = 0; nf < 4; ++nf)
#pragma unroll
        for (int kc = 0; kc < 2; ++kc)
          s[nf] = __builtin_amdgcn_mfma_f32_16x16x32_bf16(qfr[kc], kfr[nf][kc], s[nf], 0, 0, 0);
      // ---- V fragments issued early (overlap with softmax VALU) ----
      bf16x8 vfr[4][2];
#pragma unroll
      for (int df = 0; df < 4; ++df)
#pragma unroll
        for (int kc = 0; kc < 2; ++kc) {
          int row = df * 16 + lr;
          int slot = (kc * 4 + hi) ^ (row & 7);
          vfr[df][kc] = *reinterpret_cast<const bf16x8*>(vbuf + row * 128 + slot * 16);
        }
      // ---- causal mask (diagonal KV block only) ----
      if (kb == qt) {
#pragma unroll
        for (int nf = 0; nf < 4; ++nf)
#pragma unroll
          for (int r = 0; r < 4; ++r) {
            int q = qbase + hi * 4 + r;
            int kv = kb * 64 + nf * 16 + lr;
            if (kv > q) s[nf][r] = -1e30f;
          }
      }
      // ---- online softmax (row = q distributed over r; reduce across lr) --
      float rm[4];
#pragma unroll
      for (int r = 0; r < 4; ++r)
        rm[r] = fmaxf(fmaxf(s[0][r], s[1][r]), fmaxf(s[2][r], s[3][r]));
#pragma unroll
      for (int r = 0; r < 4; ++r) {
        rm[r] = fmaxf(rm[r], __shfl_xor(rm[r], 1));
        rm[r] = fmaxf(rm[r], __shfl_xor(rm[r], 2));
        rm[r] = fmaxf(rm[r], __shfl_xor(rm[r], 4));
        rm[r] = fmaxf(rm[r], __shfl_xor(rm[r], 8));
      }
#pragma unroll
      for (int r = 0; r < 4; ++r) {
        float mn = fmaxf(mrun[r], rm[r]);
        float al = __expf(mrun[r] - mn);
        mrun[r] = mn;
        float ps = 0.f;
#pragma unroll
        for (int nf = 0; nf < 4; ++nf) {
          float p = __expf(s[nf][r] - mn);
          s[nf][r] = p;
          ps += p;
        }
        lpart[r] = lpart[r] * al + ps;
#pragma unroll
        for (int df = 0; df < 4; ++df) o[df][r] *= al;
      }
      // ---- P (bf16) -> wave-private slab of lQP, swizzled ----
      char* pb = (char*)lQP + w * 2048;
#pragma unroll
      for (int nf = 0; nf < 4; ++nf)
#pragma unroll
        for (int r = 0; r < 4; ++r) {
          int rp = hi * 4 + r;
          int col = nf * 16 + lr;
          int slot = (col >> 3) ^ (rp & 7);
          *reinterpret_cast<unsigned short*>(pb + rp * 128 + slot * 16 + (col & 7) * 2) =
              f2bf(s[nf][r]);
        }
      asm volatile("s_waitcnt lgkmcnt(0)" ::: "memory");
      __builtin_amdgcn_sched_barrier(0);
      // ---- O += P V ----
      bf16x8 pfr[2];
#pragma unroll
      for (int kc = 0; kc < 2; ++kc) {
        int row = lr;
        int slot = (kc * 4 + hi) ^ (row & 7);
        pfr[kc] = *reinterpret_cast<const bf16x8*>(pb + row * 128 + slot * 16);
      }
#pragma unroll
      for (int df = 0; df < 4; ++df)
#pragma unroll
        for (int kc = 0; kc < 2; ++kc)
          o[df] = __builtin_amdgcn_mfma_f32_16x16x32_bf16(pfr[kc], vfr[df][kc], o[df], 0, 0, 0);
      // ---- end of iteration: full fence + barrier ----
      __syncthreads();
    }

    // ---- finalize: row-sum, normalize, store bf16 [b,t][h*64+d] ----
#pragma unroll
    for (int r = 0; r < 4; ++r) {
      float l = lpart[r];
      l += __shfl_xor(l, 1);
      l += __shfl_xor(l, 2);
      l += __shfl_xor(l, 4);
      l += __shfl_xor(l, 8);
      float inv = 1.0f / l;
      int qrow = qbase + hi * 4 + r;
#pragma unroll
      for (int df = 0; df < 4; ++df)
        Out[(size_t)(b * 1024 + qrow) * 1024 + h * 64 + df * 16 + lr] = f2bf(o[df][r] * inv);
    }
    __syncthreads();   // protect lQP before pass B restages Q
  }
}

// ---------------- LayerNorm over E=1024, wave per row -----------------------
__global__ __launch_bounds__(256) void lnorm(const unsigned short* __restrict__ X,
                                             unsigned short* __restrict__ Y,
                                             const float* __restrict__ gamma,
                                             const float* __restrict__ beta) {
  int rowi = (int)blockIdx.x * 4 + ((int)threadIdx.x >> 6);
  int lane = (int)threadIdx.x & 63;
  const unsigned short* row = X + (size_t)rowi * 1024;
  u16x8 v0 = reinterpret_cast<const u16x8*>(row)[lane];
  u16x8 v1 = reinterpret_cast<const u16x8*>(row)[lane + 64];
  float f0[8], f1[8];
  float s = 0.f, sq = 0.f;
#pragma unroll
  for (int j = 0; j < 8; ++j) {
    f0[j] = bf2f(v0[j]); f1[j] = bf2f(v1[j]);
    s  += f0[j] + f1[j];
    sq += f0[j] * f0[j] + f1[j] * f1[j];
  }
#pragma unroll
  for (int m = 1; m <= 32; m <<= 1) { s += __shfl_xor(s, m); sq += __shfl_xor(sq, m); }
  float mean = s * (1.0f / 1024.0f);
  float var  = sq * (1.0f / 1024.0f) - mean * mean;
  float rstd = rsqrtf(var + 1e-5f);
  int c0 = lane * 8, c1 = 512 + lane * 8;
  u16x8 o0, o1;
#pragma unroll
  for (int j = 0; j < 8; ++j) {
    o0[j] = f2bf((f0[j] - mean) * rstd * gamma[c0 + j] + beta[c0 + j]);
    o1[j] = f2bf((f1[j] - mean) * rstd * gamma[c1 + j] + beta[c1 + j]);
  }
  reinterpret_cast<u16x8*>(Y + (size_t)rowi * 1024)[lane]      = o0;
  reinterpret_cast<u16x8*>(Y + (size_t)rowi * 1024)[lane + 64] = o1;
}

// ---------------------------------------------------------------------------
extern "C" void kernel_launch(void* const* d_in, const int* in_sizes, int n_in,
                              void* d_out, int out_size, void* d_ws, size_t ws_size,
                              hipStream_t stream) {
  (void)in_sizes; (void)n_in; (void)out_size; (void)ws_size;
  const float* x     = (const float*)d_in[0];
  const float* Wq    = (const float*)d_in[1];
  const float* Wk    = (const float*)d_in[2];
  const float* Wv    = (const float*)d_in[3];
  const float* Wo    = (const float*)d_in[4];
  const float* gamma = (const float*)d_in[5];
  const float* beta  = (const float*)d_in[6];
  char* ws = (char*)d_ws;
  unsigned short* xb   = (unsigned short*)(ws);                    //  8MB [0,8)
  unsigned short* wcat = (unsigned short*)(ws + (8u  << 20));      //  6MB [8,14)
  unsigned short* wob  = (unsigned short*)(ws + (14u << 20));      //  2MB [14,16)
  unsigned short* qkv  = (unsigned short*)(ws + (16u << 20));      // 24MB [16,40)
  unsigned short* vht  = (unsigned short*)(ws + (40u << 20));      //  8MB [40,48)
  unsigned short* att  = (unsigned short*)(ws + (48u << 20));      //  8MB [48,56)
  unsigned short* lnb  = (unsigned short*)(ws + (56u << 20));      //  8MB [56,64)

  // fused converts (scale 1/sqrt(64)=0.125 folded into Wk)
  cvt_all<<<8192, 256, 0, stream>>>(x, Wq, Wk, Wv, Wo, xb, wcat, wob);
  // QKV projection: [4096,1024] x [3072,1024]^T -> bf16 [4096,3072]
  gemm_bt<0, 128><<<768, 256, 0, stream>>>(xb, wcat, qkv, 3072, 1024);
  // V head-transpose repack
  vrepack<<<dim3(16, 16, 4), 256, 0, stream>>>(qkv, vht);
  // causal flash attention (uniform-work blocks)
  attn_fwd<<<512, 256, 0, stream>>>(qkv, vht, att);
  // LayerNorm
  lnorm<<<1024, 256, 0, stream>>>(att, lnb, gamma, beta);
  // output projection -> fp32 d_out (64x128 tile -> grid 512 = 2 blocks/CU)
  gemm_bt<1, 64><<<512, 256, 0, stream>>>(lnb, wob, (void*)d_out, 1024, 1024);
}

// Round 9
// 177.971 us; speedup vs baseline: 1.0717x; 1.0290x over previous
//
#include <hip/hip_runtime.h>
#include <stdint.h>

// ---------------------------------------------------------------------------
// Fused MHA block: x@Wq^T / x@Wk^T*scale / x@Wv^T -> causal attention with
// torch-style v.reshape(B,S,D,H) head split -> LayerNorm -> @Wo^T.
// B=4 S=1024 E=1024 H=16 D=64. All heavy math in bf16 MFMA, fp32 accum.
// ---------------------------------------------------------------------------

using bf16x8 = __attribute__((ext_vector_type(8))) short;
using f32x4  = __attribute__((ext_vector_type(4))) float;
using u16x8  = __attribute__((ext_vector_type(8))) unsigned short;

#define AS1 __attribute__((address_space(1)))
#define AS3 __attribute__((address_space(3)))

__device__ __forceinline__ void gload16(const void* g, void* l) {
  // async global->LDS, 16B per lane; LDS dest is wave-uniform base + lane*16
  __builtin_amdgcn_global_load_lds((const AS1 uint32_t*)g, (AS3 uint32_t*)l, 16, 0, 0);
}

__device__ __forceinline__ unsigned short f2bf(float f) {  // RNE f32->bf16
  union { float f; uint32_t u; } v; v.f = f;
  uint32_t u = v.u + 0x7fffu + ((v.u >> 16) & 1u);
  return (unsigned short)(u >> 16);
}
__device__ __forceinline__ float bf2f(unsigned short h) {
  union { uint32_t u; float f; } v; v.u = ((uint32_t)h) << 16;
  return v.f;
}

// ---------------- fused fp32 -> bf16 converts (one launch) ------------------
// regions (float4 units): x 1048576 | Wq 262144 | Wk 262144 (x0.125)
//                         | Wv 262144 | Wo 262144
__global__ __launch_bounds__(256) void cvt_all(const float* __restrict__ x,
                                               const float* __restrict__ Wq,
                                               const float* __restrict__ Wk,
                                               const float* __restrict__ Wv,
                                               const float* __restrict__ Wo,
                                               unsigned short* __restrict__ xb,
                                               unsigned short* __restrict__ wcat,
                                               unsigned short* __restrict__ wob) {
  int i = (int)blockIdx.x * 256 + (int)threadIdx.x;   // 2097152 total
  const float* src; unsigned short* dst; int off; float scale = 1.0f;
  if (i < 1048576)      { src = x;  dst = xb;             off = i; }
  else if (i < 1310720) { src = Wq; dst = wcat;           off = i - 1048576; }
  else if (i < 1572864) { src = Wk; dst = wcat + 1048576; off = i - 1310720; scale = 0.125f; }
  else if (i < 1835008) { src = Wv; dst = wcat + 2097152; off = i - 1572864; }
  else                  { src = Wo; dst = wob;            off = i - 1835008; }
  float4 v = reinterpret_cast<const float4*>(src)[off];
  ushort4 o;
  o.x = f2bf(v.x * scale);
  o.y = f2bf(v.y * scale);
  o.z = f2bf(v.z * scale);
  o.w = f2bf(v.w * scale);
  reinterpret_cast<ushort4*>(dst)[off] = o;
}

// ---------------- GEMM (A[M,K] * B[N,K]^T), dbuf BK=32 ----------------------
// TM x 128 tile, BK=32, double-buffered LDS, prefetch next K-tile at loop
// top, one __syncthreads per iteration. LDS swizzle: slot ^ (row&3)
// involution, source pre-swizzled (rule #21).
// FUSEV: blocks with tn>=16 compute V columns of QKV; they write the
// head-transposed VhT[b,h][d][s] DIRECTLY from accumulators (8B/lane,
// s-contiguous; lines complete across mi) instead of qkv -> vrepack gone.
template<int OUTF32, int TM, int FUSEV>
__global__ __launch_bounds__(256, 3) void gemm_bt(const unsigned short* __restrict__ A,
                                                  const unsigned short* __restrict__ B,
                                                  void* __restrict__ Cv,
                                                  unsigned short* __restrict__ Vht,
                                                  int N, int K) {
  constexpr int MI = TM / 32;   // 16-row fragments per wave in M
  __shared__ __align__(16) unsigned short lA[2][TM * 32];
  __shared__ __align__(16) unsigned short lB[2][128 * 32];
  const int tn_cnt = N >> 7;
  const int nwg = gridDim.x;
  int bid = (int)blockIdx.x;
  int bid2 = (bid & 7) * (nwg >> 3) + (bid >> 3);   // XCD swizzle (nwg%8==0)
  int tm = bid2 / tn_cnt, tn = bid2 % tn_cnt;
  int t = (int)threadIdx.x;
  int w = t >> 6, lane = t & 63, lr = lane & 15, hi = lane >> 4;
  int wr = w >> 1, wc = w & 1;

  auto stage = [&](int kt, int buf) {
#pragma unroll
    for (int j = 0; j < TM / 64; ++j) {
      int ch = j * 256 + t;
      int row = ch >> 2, slot = ch & 3;
      gload16(A + (size_t)(tm * TM + row) * K + kt * 32 + ((slot ^ (row & 3)) << 3),
              (char*)lA[buf] + j * 4096 + w * 1024);
    }
#pragma unroll
    for (int j = 0; j < 2; ++j) {
      int ch = j * 256 + t;
      int row = ch >> 2, slot = ch & 3;
      gload16(B + (size_t)(tn * 128 + row) * K + kt * 32 + ((slot ^ (row & 3)) << 3),
              (char*)lB[buf] + j * 4096 + w * 1024);
    }
  };

  f32x4 acc[MI][4] = {};
  stage(0, 0);
  __syncthreads();
  const int NT = K >> 5;
  for (int kt = 0; kt < NT; ++kt) {
    int cur = kt & 1;
    if (kt + 1 < NT) stage(kt + 1, cur ^ 1);
    const char* pa = (const char*)lA[cur];
    const char* pb = (const char*)lB[cur];
    bf16x8 af[MI], bfr[4];
#pragma unroll
    for (int mi = 0; mi < MI; ++mi) {
      int row = wr * (TM / 2) + mi * 16 + lr;
      int slot = hi ^ (row & 3);
      af[mi] = *reinterpret_cast<const bf16x8*>(pa + row * 64 + slot * 16);
    }
#pragma unroll
    for (int ni = 0; ni < 4; ++ni) {
      int row = wc * 64 + ni * 16 + lr;
      int slot = hi ^ (row & 3);
      bfr[ni] = *reinterpret_cast<const bf16x8*>(pb + row * 64 + slot * 16);
    }
#pragma unroll
    for (int mi = 0; mi < MI; ++mi)
#pragma unroll
      for (int ni = 0; ni < 4; ++ni)
        acc[mi][ni] = __builtin_amdgcn_mfma_f32_16x16x32_bf16(af[mi], bfr[ni], acc[mi][ni], 0, 0, 0);
    __syncthreads();
  }
  // C/D layout: col = lane&15, row = (lane>>4)*4 + reg   [m89-verified]
  if (FUSEV && tn >= 16) {
    // V columns: write VhT[b,h][d][s] directly. cv = col-2048; d=cv>>4; h=cv&15=lr.
#pragma unroll
    for (int mi = 0; mi < MI; ++mi) {
      size_t row0 = (size_t)(tm * TM + wr * (TM / 2) + mi * 16 + hi * 4);
      int bb = (int)(row0 >> 10), ss = (int)(row0 & 1023);
#pragma unroll
      for (int ni = 0; ni < 4; ++ni) {
        int cv0 = (tn - 16) * 128 + wc * 64 + ni * 16;
        int d = cv0 >> 4;
        ushort4 pk;
        pk.x = f2bf(acc[mi][ni][0]);
        pk.y = f2bf(acc[mi][ni][1]);
        pk.z = f2bf(acc[mi][ni][2]);
        pk.w = f2bf(acc[mi][ni][3]);
        *reinterpret_cast<ushort4*>(Vht + ((size_t)(bb * 16 + lr) * 64 + d) * 1024 + ss) = pk;
      }
    }
  } else {
#pragma unroll
    for (int mi = 0; mi < MI; ++mi) {
#pragma unroll
      for (int r = 0; r < 4; ++r) {
        size_t row = (size_t)(tm * TM + wr * (TM / 2) + mi * 16 + hi * 4 + r);
#pragma unroll
        for (int ni = 0; ni < 4; ++ni) {
          int col = tn * 128 + wc * 64 + ni * 16 + lr;
          float v = acc[mi][ni][r];
          if (OUTF32) reinterpret_cast<float*>(Cv)[row * N + col] = v;
          else        reinterpret_cast<unsigned short*>(Cv)[row * N + col] = f2bf(v);
        }
      }
    }
  }
}

// ---------------- flash attention (causal), bf16 MFMA -----------------------
// Uniform-work blocks (dispatch-order-proof): grid 512 = 64 (b,h) x 8 pair
// ids; each block runs q-tiles qtA=j and qtB=15-j (64 rows each). KVBLK=128:
// nkb(qt) = (qt+2)>>1, and nkb(j)+nkb(15-j) == 9 for all j -> every block
// does exactly 9 KV iterations. 32 MFMA/iter/wave, half the barriers of the
// KVBLK=64 variant at equal staged bytes.
// LDS 80KB: K[2][128x64] + V[2][64x128] + QP slab 16KB (Q [64][64] in
// prologue; per-wave P [16][128] slabs in the loop). 2 blocks/CU.
// Swizzles: byte slot ^ (row&7) involution everywhere, sources pre-swizzled
// (rule #21). P write/read use the same involution.
__global__ __launch_bounds__(256, 2) void attn_fwd(const unsigned short* __restrict__ QKV,
                                                   const unsigned short* __restrict__ VhT,
                                                   unsigned short* __restrict__ Out) {
  __shared__ __align__(16) unsigned short lK[2][128 * 64];
  __shared__ __align__(16) unsigned short lV[2][64 * 128];
  __shared__ __align__(16) unsigned short lQP[8192];   // 16KB
  int bid = (int)blockIdx.x;
  int bh = bid >> 3, j = bid & 7;
  int b = bh >> 4, h = bh & 15;
  int t = (int)threadIdx.x;
  int w = t >> 6, lane = t & 63, lr = lane & 15, hi = lane >> 4;
  (void)lane;

  auto stageKV = [&](int kb, int buf) {
    // K tile [128 kv][64 d]
#pragma unroll
    for (int i = 0; i < 4; ++i) {
      int c = i * 256 + t;
      int row = c >> 3, slot = c & 7;
      gload16(QKV + (size_t)(b * 1024 + kb * 128 + row) * 3072 + 1024 + h * 64 + ((slot ^ (row & 7)) << 3),
              (char*)lK[buf] + i * 4096 + w * 1024);
    }
    // V tile [64 d][128 s]
#pragma unroll
    for (int i = 0; i < 4; ++i) {
      int c = i * 256 + t;
      int row = c >> 4, sl = c & 15;
      gload16(VhT + (size_t)(bh * 64 + row) * 1024 + kb * 128 + ((sl ^ (row & 7)) << 3),
              (char*)lV[buf] + i * 4096 + w * 1024);
    }
  };

#pragma unroll 1
  for (int pass = 0; pass < 2; ++pass) {
    int qt = pass ? (15 - j) : j;
    // ---- stage Q tile [64][64] into lQP + first K/V tile ----
#pragma unroll
    for (int i = 0; i < 2; ++i) {
      int c = i * 256 + t;
      int row = c >> 3, slot = c & 7;
      gload16(QKV + (size_t)(b * 1024 + qt * 64 + row) * 3072 + h * 64 + ((slot ^ (row & 7)) << 3),
              (char*)lQP + i * 4096 + w * 1024);
    }
    stageKV(0, 0);
    __syncthreads();

    // ---- Q fragments (A-operand: row=lane&15, k=(lane>>4)*8+j) ----
    bf16x8 qfr[2];
#pragma unroll
    for (int kc = 0; kc < 2; ++kc) {
      int row = w * 16 + lr;
      int slot = (kc * 4 + hi) ^ (row & 7);
      qfr[kc] = *reinterpret_cast<const bf16x8*>((const char*)lQP + row * 128 + slot * 16);
    }
    int qbase = qt * 64 + w * 16;
    f32x4 o[4] = {};
    float mrun[4], lpart[4];
#pragma unroll
    for (int r = 0; r < 4; ++r) { mrun[r] = -1e30f; lpart[r] = 0.f; }

    int nkb = (qt + 2) >> 1;
    for (int kb = 0; kb < nkb; ++kb) {
      int cur = kb & 1;
      if (kb + 1 < nkb) stageKV(kb + 1, cur ^ 1);
      const char* kbuf = (const char*)lK[cur];
      const char* vbuf = (const char*)lV[cur];
      // ---- S = Q K^T  (128 kv cols) ----
      bf16x8 kfr[8][2];
#pragma unroll
      for (int nf = 0; nf < 8; ++nf)
#pragma unroll
        for (int kc = 0; kc < 2; ++kc) {
          int row = nf * 16 + lr;
          int slot = (kc * 4 + hi) ^ (row & 7);
          kfr[nf][kc] = *reinterpret_cast<const bf16x8*>(kbuf + row * 128 + slot * 16);
        }
      f32x4 s[8] = {};
#pragma unroll
      for (int nf = 0; nf < 8; ++nf)
#pragma unroll
        for (int kc = 0; kc < 2; ++kc)
          s[nf] = __builtin_amdgcn_mfma_f32_16x16x32_bf16(qfr[kc], kfr[nf][kc], s[nf], 0, 0, 0);
      // ---- V fragments issued early (overlap with softmax VALU) ----
      bf16x8 vfr[4][4];
#pragma unroll
      for (int df = 0; df < 4; ++df)
#pragma unroll
        for (int kc = 0; kc < 4; ++kc) {
          int row = df * 16 + lr;
          int slot = (kc * 4 + hi) ^ (row & 7);
          vfr[df][kc] = *reinterpret_cast<const bf16x8*>(vbuf + row * 256 + slot * 16);
        }
      // ---- causal mask (last KV block only; rows past S-end get -1e30 -> 0)
      if (kb == nkb - 1) {
#pragma unroll
        for (int nf = 0; nf < 8; ++nf)
#pragma unroll
          for (int r = 0; r < 4; ++r) {
            int q = qbase + hi * 4 + r;
            int kv = kb * 128 + nf * 16 + lr;
            if (kv > q) s[nf][r] = -1e30f;
          }
      }
      // ---- online softmax (q rows over r; reduce across lr lanes) ----
      float rm[4];
#pragma unroll
      for (int r = 0; r < 4; ++r) {
        float m0 = fmaxf(fmaxf(s[0][r], s[1][r]), fmaxf(s[2][r], s[3][r]));
        float m1 = fmaxf(fmaxf(s[4][r], s[5][r]), fmaxf(s[6][r], s[7][r]));
        rm[r] = fmaxf(m0, m1);
      }
#pragma unroll
      for (int r = 0; r < 4; ++r) {
        rm[r] = fmaxf(rm[r], __shfl_xor(rm[r], 1));
        rm[r] = fmaxf(rm[r], __shfl_xor(rm[r], 2));
        rm[r] = fmaxf(rm[r], __shfl_xor(rm[r], 4));
        rm[r] = fmaxf(rm[r], __shfl_xor(rm[r], 8));
      }
#pragma unroll
      for (int r = 0; r < 4; ++r) {
        float mn = fmaxf(mrun[r], rm[r]);
        float al = __expf(mrun[r] - mn);
        mrun[r] = mn;
        float ps = 0.f;
#pragma unroll
        for (int nf = 0; nf < 8; ++nf) {
          float p = __expf(s[nf][r] - mn);
          s[nf][r] = p;
          ps += p;
        }
        lpart[r] = lpart[r] * al + ps;
#pragma unroll
        for (int df = 0; df < 4; ++df) o[df][r] *= al;
      }
      // ---- P (bf16) -> wave-private slab [16][128] of lQP, swizzled ----
      char* pb = (char*)lQP + w * 4096;
#pragma unroll
      for (int nf = 0; nf < 8; ++nf)
#pragma unroll
        for (int r = 0; r < 4; ++r) {
          int rp = hi * 4 + r;
          int col = nf * 16 + lr;
          int slot = (col >> 3) ^ (rp & 7);
          *reinterpret_cast<unsigned short*>(pb + rp * 256 + slot * 16 + (col & 7) * 2) =
              f2bf(s[nf][r]);
        }
      asm volatile("s_waitcnt lgkmcnt(0)" ::: "memory");
      __builtin_amdgcn_sched_barrier(0);
      // ---- O += P V ----
      bf16x8 pfr[4];
#pragma unroll
      for (int kc = 0; kc < 4; ++kc) {
        int slot = (kc * 4 + hi) ^ (lr & 7);
        pfr[kc] = *reinterpret_cast<const bf16x8*>(pb + lr * 256 + slot * 16);
      }
#pragma unroll
      for (int df = 0; df < 4; ++df)
#pragma unroll
        for (int kc = 0; kc < 4; ++kc)
          o[df] = __builtin_amdgcn_mfma_f32_16x16x32_bf16(pfr[kc], vfr[df][kc], o[df], 0, 0, 0);
      // ---- end of iteration: full fence + barrier (drains prefetch) ----
      __syncthreads();
    }

    // ---- finalize: row-sum, normalize, store bf16 [b,t][h*64+d] ----
#pragma unroll
    for (int r = 0; r < 4; ++r) {
      float l = lpart[r];
      l += __shfl_xor(l, 1);
      l += __shfl_xor(l, 2);
      l += __shfl_xor(l, 4);
      l += __shfl_xor(l, 8);
      float inv = 1.0f / l;
      int qrow = qbase + hi * 4 + r;
#pragma unroll
      for (int df = 0; df < 4; ++df)
        Out[(size_t)(b * 1024 + qrow) * 1024 + h * 64 + df * 16 + lr] = f2bf(o[df][r] * inv);
    }
    __syncthreads();   // protect lQP/lK/lV before next pass restages
  }
}

// ---------------- LayerNorm over E=1024, wave per row -----------------------
__global__ __launch_bounds__(256) void lnorm(const unsigned short* __restrict__ X,
                                             unsigned short* __restrict__ Y,
                                             const float* __restrict__ gamma,
                                             const float* __restrict__ beta) {
  int rowi = (int)blockIdx.x * 4 + ((int)threadIdx.x >> 6);
  int lane = (int)threadIdx.x & 63;
  const unsigned short* row = X + (size_t)rowi * 1024;
  u16x8 v0 = reinterpret_cast<const u16x8*>(row)[lane];
  u16x8 v1 = reinterpret_cast<const u16x8*>(row)[lane + 64];
  float f0[8], f1[8];
  float s = 0.f, sq = 0.f;
#pragma unroll
  for (int j = 0; j < 8; ++j) {
    f0[j] = bf2f(v0[j]); f1[j] = bf2f(v1[j]);
    s  += f0[j] + f1[j];
    sq += f0[j] * f0[j] + f1[j] * f1[j];
  }
#pragma unroll
  for (int m = 1; m <= 32; m <<= 1) { s += __shfl_xor(s, m); sq += __shfl_xor(sq, m); }
  float mean = s * (1.0f / 1024.0f);
  float var  = sq * (1.0f / 1024.0f) - mean * mean;
  float rstd = rsqrtf(var + 1e-5f);
  int c0 = lane * 8, c1 = 512 + lane * 8;
  u16x8 o0, o1;
#pragma unroll
  for (int j = 0; j < 8; ++j) {
    o0[j] = f2bf((f0[j] - mean) * rstd * gamma[c0 + j] + beta[c0 + j]);
    o1[j] = f2bf((f1[j] - mean) * rstd * gamma[c1 + j] + beta[c1 + j]);
  }
  reinterpret_cast<u16x8*>(Y + (size_t)rowi * 1024)[lane]      = o0;
  reinterpret_cast<u16x8*>(Y + (size_t)rowi * 1024)[lane + 64] = o1;
}

// ---------------------------------------------------------------------------
extern "C" void kernel_launch(void* const* d_in, const int* in_sizes, int n_in,
                              void* d_out, int out_size, void* d_ws, size_t ws_size,
                              hipStream_t stream) {
  (void)in_sizes; (void)n_in; (void)out_size; (void)ws_size;
  const float* x     = (const float*)d_in[0];
  const float* Wq    = (const float*)d_in[1];
  const float* Wk    = (const float*)d_in[2];
  const float* Wv    = (const float*)d_in[3];
  const float* Wo    = (const float*)d_in[4];
  const float* gamma = (const float*)d_in[5];
  const float* beta  = (const float*)d_in[6];
  char* ws = (char*)d_ws;
  unsigned short* xb   = (unsigned short*)(ws);                    //  8MB [0,8)
  unsigned short* wcat = (unsigned short*)(ws + (8u  << 20));      //  6MB [8,14)
  unsigned short* wob  = (unsigned short*)(ws + (14u << 20));      //  2MB [14,16)
  unsigned short* qkv  = (unsigned short*)(ws + (16u << 20));      // 24MB [16,40)
  unsigned short* vht  = (unsigned short*)(ws + (40u << 20));      //  8MB [40,48)
  unsigned short* att  = (unsigned short*)(ws + (48u << 20));      //  8MB [48,56)
  unsigned short* lnb  = (unsigned short*)(ws + (56u << 20));      //  8MB [56,64)

  // fused converts (scale 1/sqrt(64)=0.125 folded into Wk)
  cvt_all<<<8192, 256, 0, stream>>>(x, Wq, Wk, Wv, Wo, xb, wcat, wob);
  // QKV projection; V columns go straight to VhT (vrepack fused)
  gemm_bt<0, 128, 1><<<768, 256, 0, stream>>>(xb, wcat, qkv, vht, 3072, 1024);
  // causal flash attention (uniform-work blocks, KVBLK=128)
  attn_fwd<<<512, 256, 0, stream>>>(qkv, vht, att);
  // LayerNorm
  lnorm<<<1024, 256, 0, stream>>>(att, lnb, gamma, beta);
  // output projection -> fp32 d_out (64x128 tile -> grid 512 = 2 blocks/CU)
  gemm_bt<1, 64, 0><<<512, 256, 0, stream>>>(lnb, wob, (void*)d_out, nullptr, 1024, 1024);
}

// Round 10
// 172.284 us; speedup vs baseline: 1.1071x; 1.0330x over previous
//
#include <hip/hip_runtime.h>
#include <stdint.h>

// ---------------------------------------------------------------------------
// Fused MHA block: x@Wq^T / x@Wk^T*scale / x@Wv^T -> causal attention with
// torch-style v.reshape(B,S,D,H) head split -> LayerNorm -> @Wo^T.
// B=4 S=1024 E=1024 H=16 D=64. All heavy math in bf16 MFMA, fp32 accum.
// ---------------------------------------------------------------------------

using bf16x8 = __attribute__((ext_vector_type(8))) short;
using f32x4  = __attribute__((ext_vector_type(4))) float;
using u16x8  = __attribute__((ext_vector_type(8))) unsigned short;

#define AS1 __attribute__((address_space(1)))
#define AS3 __attribute__((address_space(3)))

__device__ __forceinline__ void gload16(const void* g, void* l) {
  // async global->LDS, 16B per lane; LDS dest is wave-uniform base + lane*16
  __builtin_amdgcn_global_load_lds((const AS1 uint32_t*)g, (AS3 uint32_t*)l, 16, 0, 0);
}

__device__ __forceinline__ unsigned short f2bf(float f) {  // RNE f32->bf16
  union { float f; uint32_t u; } v; v.f = f;
  uint32_t u = v.u + 0x7fffu + ((v.u >> 16) & 1u);
  return (unsigned short)(u >> 16);
}
__device__ __forceinline__ float bf2f(unsigned short h) {
  union { uint32_t u; float f; } v; v.u = ((uint32_t)h) << 16;
  return v.f;
}

// ---------------- fused fp32 -> bf16 converts (one launch) ------------------
// regions (float4 units): x 1048576 | Wq 262144 | Wk 262144 (x0.125)
//                         | Wv 262144 | Wo 262144
__global__ __launch_bounds__(256) void cvt_all(const float* __restrict__ x,
                                               const float* __restrict__ Wq,
                                               const float* __restrict__ Wk,
                                               const float* __restrict__ Wv,
                                               const float* __restrict__ Wo,
                                               unsigned short* __restrict__ xb,
                                               unsigned short* __restrict__ wcat,
                                               unsigned short* __restrict__ wob) {
  int i = (int)blockIdx.x * 256 + (int)threadIdx.x;   // 2097152 total
  const float* src; unsigned short* dst; int off; float scale = 1.0f;
  if (i < 1048576)      { src = x;  dst = xb;             off = i; }
  else if (i < 1310720) { src = Wq; dst = wcat;           off = i - 1048576; }
  else if (i < 1572864) { src = Wk; dst = wcat + 1048576; off = i - 1310720; scale = 0.125f; }
  else if (i < 1835008) { src = Wv; dst = wcat + 2097152; off = i - 1572864; }
  else                  { src = Wo; dst = wob;            off = i - 1835008; }
  float4 v = reinterpret_cast<const float4*>(src)[off];
  ushort4 o;
  o.x = f2bf(v.x * scale);
  o.y = f2bf(v.y * scale);
  o.z = f2bf(v.z * scale);
  o.w = f2bf(v.w * scale);
  reinterpret_cast<ushort4*>(dst)[off] = o;
}

// ---------------- GEMM (A[M,K] * B[N,K]^T), dbuf BK=32 ----------------------
// TM x 128 tile, BK=32, double-buffered LDS, prefetch next K-tile at loop
// top, one __syncthreads per iteration. LDS swizzle: slot ^ (row&3)
// involution, source pre-swizzled (rule #21).
// XCD 2-D rectangle mapping: XCD x (bid%8) owns a TMC x TNC block-tile so its
// L2 footprint (A TMC rows + B TNC cols) fits the 4MB per-XCD L2.
// FUSEV: blocks with tn>=16 compute V columns of QKV; they write the
// head-transposed VhT[b,h][d][s] DIRECTLY from accumulators.
template<int OUTF32, int TM, int FUSEV, int TMC, int TNC, int XTM, int XTN>
__global__ __launch_bounds__(256, 3) void gemm_bt(const unsigned short* __restrict__ A,
                                                  const unsigned short* __restrict__ B,
                                                  void* __restrict__ Cv,
                                                  unsigned short* __restrict__ Vht,
                                                  int N, int K) {
  constexpr int MI = TM / 32;   // 16-row fragments per wave in M
  __shared__ __align__(16) unsigned short lA[2][TM * 32];
  __shared__ __align__(16) unsigned short lB[2][128 * 32];
  int bid = (int)blockIdx.x;
  int x = bid & 7, lo = bid >> 3;
  int tm = (x % XTM) * TMC + lo / TNC;
  int tn = (x / XTM) * TNC + lo % TNC;
  int t = (int)threadIdx.x;
  int w = t >> 6, lane = t & 63, lr = lane & 15, hi = lane >> 4;
  int wr = w >> 1, wc = w & 1;

  auto stage = [&](int kt, int buf) {
#pragma unroll
    for (int j = 0; j < TM / 64; ++j) {
      int ch = j * 256 + t;
      int row = ch >> 2, slot = ch & 3;
      gload16(A + (size_t)(tm * TM + row) * K + kt * 32 + ((slot ^ (row & 3)) << 3),
              (char*)lA[buf] + j * 4096 + w * 1024);
    }
#pragma unroll
    for (int j = 0; j < 2; ++j) {
      int ch = j * 256 + t;
      int row = ch >> 2, slot = ch & 3;
      gload16(B + (size_t)(tn * 128 + row) * K + kt * 32 + ((slot ^ (row & 3)) << 3),
              (char*)lB[buf] + j * 4096 + w * 1024);
    }
  };

  f32x4 acc[MI][4] = {};
  stage(0, 0);
  __syncthreads();
  const int NT = K >> 5;
  for (int kt = 0; kt < NT; ++kt) {
    int cur = kt & 1;
    if (kt + 1 < NT) stage(kt + 1, cur ^ 1);
    const char* pa = (const char*)lA[cur];
    const char* pb = (const char*)lB[cur];
    bf16x8 af[MI], bfr[4];
#pragma unroll
    for (int mi = 0; mi < MI; ++mi) {
      int row = wr * (TM / 2) + mi * 16 + lr;
      int slot = hi ^ (row & 3);
      af[mi] = *reinterpret_cast<const bf16x8*>(pa + row * 64 + slot * 16);
    }
#pragma unroll
    for (int ni = 0; ni < 4; ++ni) {
      int row = wc * 64 + ni * 16 + lr;
      int slot = hi ^ (row & 3);
      bfr[ni] = *reinterpret_cast<const bf16x8*>(pb + row * 64 + slot * 16);
    }
#pragma unroll
    for (int mi = 0; mi < MI; ++mi)
#pragma unroll
      for (int ni = 0; ni < 4; ++ni)
        acc[mi][ni] = __builtin_amdgcn_mfma_f32_16x16x32_bf16(af[mi], bfr[ni], acc[mi][ni], 0, 0, 0);
    __syncthreads();
  }
  // C/D layout: col = lane&15, row = (lane>>4)*4 + reg   [m89-verified]
  if (FUSEV && tn >= 16) {
    // V columns: write VhT[b,h][d][s] directly. cv = col-2048; d=cv>>4; h=cv&15=lr.
#pragma unroll
    for (int mi = 0; mi < MI; ++mi) {
      size_t row0 = (size_t)(tm * TM + wr * (TM / 2) + mi * 16 + hi * 4);
      int bb = (int)(row0 >> 10), ss = (int)(row0 & 1023);
#pragma unroll
      for (int ni = 0; ni < 4; ++ni) {
        int cv0 = (tn - 16) * 128 + wc * 64 + ni * 16;
        int d = cv0 >> 4;
        ushort4 pk;
        pk.x = f2bf(acc[mi][ni][0]);
        pk.y = f2bf(acc[mi][ni][1]);
        pk.z = f2bf(acc[mi][ni][2]);
        pk.w = f2bf(acc[mi][ni][3]);
        *reinterpret_cast<ushort4*>(Vht + ((size_t)(bb * 16 + lr) * 64 + d) * 1024 + ss) = pk;
      }
    }
  } else {
#pragma unroll
    for (int mi = 0; mi < MI; ++mi) {
#pragma unroll
      for (int r = 0; r < 4; ++r) {
        size_t row = (size_t)(tm * TM + wr * (TM / 2) + mi * 16 + hi * 4 + r);
#pragma unroll
        for (int ni = 0; ni < 4; ++ni) {
          int col = tn * 128 + wc * 64 + ni * 16 + lr;
          float v = acc[mi][ni][r];
          if (OUTF32) reinterpret_cast<float*>(Cv)[row * N + col] = v;
          else        reinterpret_cast<unsigned short*>(Cv)[row * N + col] = f2bf(v);
        }
      }
    }
  }
}

// ---------------- flash attention (causal), bf16 MFMA -----------------------
// Uniform-work blocks + XCD locality: bid = j*64 + bh, so XCD (bid%8) = bh%8
// -> all 8 pair-blocks sharing one (b,h) K/V stream live on ONE XCD; per-XCD
// working set (8 bh x 256KB K/V + Q) ~3MB < 4MB L2. Each block runs q-tiles
// qtA=j, qtB=15-j; nkb(j)+nkb(15-j)==9 for all j -> uniform work.
// KVBLK=128, 32 MFMA/iter/wave. LDS 80KB -> 2 blocks/CU.
// Swizzles: byte slot ^ (row&7) involution everywhere, sources pre-swizzled
// (rule #21). P write/read use the same involution.
__global__ __launch_bounds__(256, 2) void attn_fwd(const unsigned short* __restrict__ QKV,
                                                   const unsigned short* __restrict__ VhT,
                                                   unsigned short* __restrict__ Out) {
  __shared__ __align__(16) unsigned short lK[2][128 * 64];
  __shared__ __align__(16) unsigned short lV[2][64 * 128];
  __shared__ __align__(16) unsigned short lQP[8192];   // 16KB
  int bid = (int)blockIdx.x;
  int bh = bid & 63, j = bid >> 6;      // XCD-local: bid%8 == bh%8
  int b = bh >> 4, h = bh & 15;
  int t = (int)threadIdx.x;
  int w = t >> 6, lane = t & 63, lr = lane & 15, hi = lane >> 4;
  (void)lane;

  auto stageKV = [&](int kb, int buf) {
    // K tile [128 kv][64 d]
#pragma unroll
    for (int i = 0; i < 4; ++i) {
      int c = i * 256 + t;
      int row = c >> 3, slot = c & 7;
      gload16(QKV + (size_t)(b * 1024 + kb * 128 + row) * 3072 + 1024 + h * 64 + ((slot ^ (row & 7)) << 3),
              (char*)lK[buf] + i * 4096 + w * 1024);
    }
    // V tile [64 d][128 s]
#pragma unroll
    for (int i = 0; i < 4; ++i) {
      int c = i * 256 + t;
      int row = c >> 4, sl = c & 15;
      gload16(VhT + (size_t)(bh * 64 + row) * 1024 + kb * 128 + ((sl ^ (row & 7)) << 3),
              (char*)lV[buf] + i * 4096 + w * 1024);
    }
  };

#pragma unroll 1
  for (int pass = 0; pass < 2; ++pass) {
    int qt = pass ? (15 - j) : j;
    // ---- stage Q tile [64][64] into lQP + first K/V tile ----
#pragma unroll
    for (int i = 0; i < 2; ++i) {
      int c = i * 256 + t;
      int row = c >> 3, slot = c & 7;
      gload16(QKV + (size_t)(b * 1024 + qt * 64 + row) * 3072 + h * 64 + ((slot ^ (row & 7)) << 3),
              (char*)lQP + i * 4096 + w * 1024);
    }
    stageKV(0, 0);
    __syncthreads();

    // ---- Q fragments (A-operand: row=lane&15, k=(lane>>4)*8+j) ----
    bf16x8 qfr[2];
#pragma unroll
    for (int kc = 0; kc < 2; ++kc) {
      int row = w * 16 + lr;
      int slot = (kc * 4 + hi) ^ (row & 7);
      qfr[kc] = *reinterpret_cast<const bf16x8*>((const char*)lQP + row * 128 + slot * 16);
    }
    int qbase = qt * 64 + w * 16;
    f32x4 o[4] = {};
    float mrun[4], lpart[4];
#pragma unroll
    for (int r = 0; r < 4; ++r) { mrun[r] = -1e30f; lpart[r] = 0.f; }

    int nkb = (qt + 2) >> 1;
    for (int kb = 0; kb < nkb; ++kb) {
      int cur = kb & 1;
      if (kb + 1 < nkb) stageKV(kb + 1, cur ^ 1);
      const char* kbuf = (const char*)lK[cur];
      const char* vbuf = (const char*)lV[cur];
      // ---- S = Q K^T  (128 kv cols) ----
      bf16x8 kfr[8][2];
#pragma unroll
      for (int nf = 0; nf < 8; ++nf)
#pragma unroll
        for (int kc = 0; kc < 2; ++kc) {
          int row = nf * 16 + lr;
          int slot = (kc * 4 + hi) ^ (row & 7);
          kfr[nf][kc] = *reinterpret_cast<const bf16x8*>(kbuf + row * 128 + slot * 16);
        }
      f32x4 s[8] = {};
#pragma unroll
      for (int nf = 0; nf < 8; ++nf)
#pragma unroll
        for (int kc = 0; kc < 2; ++kc)
          s[nf] = __builtin_amdgcn_mfma_f32_16x16x32_bf16(qfr[kc], kfr[nf][kc], s[nf], 0, 0, 0);
      // ---- V fragments issued early (overlap with softmax VALU) ----
      bf16x8 vfr[4][4];
#pragma unroll
      for (int df = 0; df < 4; ++df)
#pragma unroll
        for (int kc = 0; kc < 4; ++kc) {
          int row = df * 16 + lr;
          int slot = (kc * 4 + hi) ^ (row & 7);
          vfr[df][kc] = *reinterpret_cast<const bf16x8*>(vbuf + row * 256 + slot * 16);
        }
      // ---- causal mask (last KV block only) ----
      if (kb == nkb - 1) {
#pragma unroll
        for (int nf = 0; nf < 8; ++nf)
#pragma unroll
          for (int r = 0; r < 4; ++r) {
            int q = qbase + hi * 4 + r;
            int kv = kb * 128 + nf * 16 + lr;
            if (kv > q) s[nf][r] = -1e30f;
          }
      }
      // ---- online softmax (q rows over r; reduce across lr lanes) ----
      float rm[4];
#pragma unroll
      for (int r = 0; r < 4; ++r) {
        float m0 = fmaxf(fmaxf(s[0][r], s[1][r]), fmaxf(s[2][r], s[3][r]));
        float m1 = fmaxf(fmaxf(s[4][r], s[5][r]), fmaxf(s[6][r], s[7][r]));
        rm[r] = fmaxf(m0, m1);
      }
#pragma unroll
      for (int r = 0; r < 4; ++r) {
        rm[r] = fmaxf(rm[r], __shfl_xor(rm[r], 1));
        rm[r] = fmaxf(rm[r], __shfl_xor(rm[r], 2));
        rm[r] = fmaxf(rm[r], __shfl_xor(rm[r], 4));
        rm[r] = fmaxf(rm[r], __shfl_xor(rm[r], 8));
      }
#pragma unroll
      for (int r = 0; r < 4; ++r) {
        float mn = fmaxf(mrun[r], rm[r]);
        float al = __expf(mrun[r] - mn);
        mrun[r] = mn;
        float ps = 0.f;
#pragma unroll
        for (int nf = 0; nf < 8; ++nf) {
          float p = __expf(s[nf][r] - mn);
          s[nf][r] = p;
          ps += p;
        }
        lpart[r] = lpart[r] * al + ps;
#pragma unroll
        for (int df = 0; df < 4; ++df) o[df][r] *= al;
      }
      // ---- P (bf16) -> wave-private slab [16][128] of lQP, swizzled ----
      char* pb = (char*)lQP + w * 4096;
#pragma unroll
      for (int nf = 0; nf < 8; ++nf)
#pragma unroll
        for (int r = 0; r < 4; ++r) {
          int rp = hi * 4 + r;
          int col = nf * 16 + lr;
          int slot = (col >> 3) ^ (rp & 7);
          *reinterpret_cast<unsigned short*>(pb + rp * 256 + slot * 16 + (col & 7) * 2) =
              f2bf(s[nf][r]);
        }
      asm volatile("s_waitcnt lgkmcnt(0)" ::: "memory");
      __builtin_amdgcn_sched_barrier(0);
      // ---- O += P V ----
      bf16x8 pfr[4];
#pragma unroll
      for (int kc = 0; kc < 4; ++kc) {
        int slot = (kc * 4 + hi) ^ (lr & 7);
        pfr[kc] = *reinterpret_cast<const bf16x8*>(pb + lr * 256 + slot * 16);
      }
#pragma unroll
      for (int df = 0; df < 4; ++df)
#pragma unroll
        for (int kc = 0; kc < 4; ++kc)
          o[df] = __builtin_amdgcn_mfma_f32_16x16x32_bf16(pfr[kc], vfr[df][kc], o[df], 0, 0, 0);
      // ---- end of iteration: full fence + barrier (drains prefetch) ----
      __syncthreads();
    }

    // ---- finalize: row-sum, normalize, store bf16 [b,t][h*64+d] ----
#pragma unroll
    for (int r = 0; r < 4; ++r) {
      float l = lpart[r];
      l += __shfl_xor(l, 1);
      l += __shfl_xor(l, 2);
      l += __shfl_xor(l, 4);
      l += __shfl_xor(l, 8);
      float inv = 1.0f / l;
      int qrow = qbase + hi * 4 + r;
#pragma unroll
      for (int df = 0; df < 4; ++df)
        Out[(size_t)(b * 1024 + qrow) * 1024 + h * 64 + df * 16 + lr] = f2bf(o[df][r] * inv);
    }
    __syncthreads();   // protect lQP/lK/lV before next pass restages
  }
}

// ---------------- LayerNorm over E=1024, wave per row -----------------------
__global__ __launch_bounds__(256) void lnorm(const unsigned short* __restrict__ X,
                                             unsigned short* __restrict__ Y,
                                             const float* __restrict__ gamma,
                                             const float* __restrict__ beta) {
  int rowi = (int)blockIdx.x * 4 + ((int)threadIdx.x >> 6);
  int lane = (int)threadIdx.x & 63;
  const unsigned short* row = X + (size_t)rowi * 1024;
  u16x8 v0 = reinterpret_cast<const u16x8*>(row)[lane];
  u16x8 v1 = reinterpret_cast<const u16x8*>(row)[lane + 64];
  float f0[8], f1[8];
  float s = 0.f, sq = 0.f;
#pragma unroll
  for (int j = 0; j < 8; ++j) {
    f0[j] = bf2f(v0[j]); f1[j] = bf2f(v1[j]);
    s  += f0[j] + f1[j];
    sq += f0[j] * f0[j] + f1[j] * f1[j];
  }
#pragma unroll
  for (int m = 1; m <= 32; m <<= 1) { s += __shfl_xor(s, m); sq += __shfl_xor(sq, m); }
  float mean = s * (1.0f / 1024.0f);
  float var  = sq * (1.0f / 1024.0f) - mean * mean;
  float rstd = rsqrtf(var + 1e-5f);
  int c0 = lane * 8, c1 = 512 + lane * 8;
  u16x8 o0, o1;
#pragma unroll
  for (int j = 0; j < 8; ++j) {
    o0[j] = f2bf((f0[j] - mean) * rstd * gamma[c0 + j] + beta[c0 + j]);
    o1[j] = f2bf((f1[j] - mean) * rstd * gamma[c1 + j] + beta[c1 + j]);
  }
  reinterpret_cast<u16x8*>(Y + (size_t)rowi * 1024)[lane]      = o0;
  reinterpret_cast<u16x8*>(Y + (size_t)rowi * 1024)[lane + 64] = o1;
}

// ---------------------------------------------------------------------------
extern "C" void kernel_launch(void* const* d_in, const int* in_sizes, int n_in,
                              void* d_out, int out_size, void* d_ws, size_t ws_size,
                              hipStream_t stream) {
  (void)in_sizes; (void)n_in; (void)out_size; (void)ws_size;
  const float* x     = (const float*)d_in[0];
  const float* Wq    = (const float*)d_in[1];
  const float* Wk    = (const float*)d_in[2];
  const float* Wv    = (const float*)d_in[3];
  const float* Wo    = (const float*)d_in[4];
  const float* gamma = (const float*)d_in[5];
  const float* beta  = (const float*)d_in[6];
  char* ws = (char*)d_ws;
  unsigned short* xb   = (unsigned short*)(ws);                    //  8MB [0,8)
  unsigned short* wcat = (unsigned short*)(ws + (8u  << 20));      //  6MB [8,14)
  unsigned short* wob  = (unsigned short*)(ws + (14u << 20));      //  2MB [14,16)
  unsigned short* qkv  = (unsigned short*)(ws + (16u << 20));      // 24MB [16,40)
  unsigned short* vht  = (unsigned short*)(ws + (40u << 20));      //  8MB [40,48)
  unsigned short* att  = (unsigned short*)(ws + (48u << 20));      //  8MB [48,56)
  unsigned short* lnb  = (unsigned short*)(ws + (56u << 20));      //  8MB [56,64)

  // fused converts (scale 1/sqrt(64)=0.125 folded into Wk)
  cvt_all<<<8192, 256, 0, stream>>>(x, Wq, Wk, Wv, Wo, xb, wcat, wob);
  // QKV projection; V columns go straight to VhT (vrepack fused).
  // XCD rect 8x12: per-XCD footprint A 2MB + B 3MB.
  gemm_bt<0, 128, 1, 8, 12, 4, 2><<<768, 256, 0, stream>>>(xb, wcat, qkv, vht, 3072, 1024);
  // causal flash attention (uniform-work blocks, KVBLK=128, XCD-local bh)
  attn_fwd<<<512, 256, 0, stream>>>(qkv, vht, att);
  // LayerNorm
  lnorm<<<1024, 256, 0, stream>>>(att, lnb, gamma, beta);
  // output projection -> fp32 d_out. XCD rect 16x4: A 2MB + B 1MB.
  gemm_bt<1, 64, 0, 16, 4, 4, 2><<<512, 256, 0, stream>>>(lnb, wob, (void*)d_out, nullptr, 1024, 1024);
}